// Round 10
// baseline (136.921 us; speedup 1.0000x reference)
//
#include <hip/hip_runtime.h>
#include <hip/hip_bf16.h>

typedef __attribute__((ext_vector_type(8))) short short8;
typedef __attribute__((ext_vector_type(4))) short short4v;
typedef __attribute__((ext_vector_type(4))) float f32x4;

#define SC_L2E 0.4561727848849353f          // (1/sqrt(10)) * log2(e)

#if __has_builtin(__builtin_amdgcn_exp2f)
#define EXP2F __builtin_amdgcn_exp2f
#else
#define EXP2F exp2f
#endif

static __device__ __forceinline__ f32x4 mfma16(short4v a, short4v b, f32x4 c) {
#if __has_builtin(__builtin_amdgcn_mfma_f32_16x16x16bf16_1k)
  return __builtin_amdgcn_mfma_f32_16x16x16bf16_1k(a, b, c, 0, 0, 0);
#else
  asm("v_mfma_f32_16x16x16_bf16 %0, %1, %2, %0" : "+v"(c) : "v"(a), "v"(b));
  return c;
#endif
}

static __device__ __forceinline__ void gload16(const void* g, void* l) {
  __builtin_amdgcn_global_load_lds((const __attribute__((address_space(1))) void*)g,
                                   (__attribute__((address_space(3))) void*)l, 16, 0, 0);
}

// ---------------- kernel 1: weight transpose + mask bias ----------------
__global__ void k_cvt_w(const float* __restrict__ Wq, const float* __restrict__ Wk,
                        const float* __restrict__ Wv, __hip_bfloat16* __restrict__ wt,
                        const int* __restrict__ mask, float* __restrict__ bias2) {
  __shared__ float T[64][65];
  const int z = blockIdx.z;
  if (z == 0 && blockIdx.y == 0) {
    const int idx = blockIdx.x * 256 + threadIdx.x;
    bias2[idx] = mask[idx] ? -12.0f : -1e30f;   // static shift M=12 folded in
  }
  const float* W = (z == 0) ? Wq : (z == 1) ? Wk : Wv;
  __hip_bfloat16* Wd = wt + (size_t)z * 1048576;
  const int n0 = blockIdx.x * 64, k0 = blockIdx.y * 64;
  const int tx = threadIdx.x & 63, ty = threadIdx.x >> 6;
#pragma unroll
  for (int r = 0; r < 16; ++r)
    T[ty + r * 4][tx] = W[(size_t)(k0 + ty + r * 4) * 1024 + n0 + tx];
  __syncthreads();
#pragma unroll
  for (int r = 0; r < 16; ++r)
    Wd[(size_t)(n0 + ty + r * 4) * 1024 + k0 + tx] = __float2bfloat16(T[tx][ty + r * 4]);
}

// ---------------- kernel 2: projection GEMM (fused fp32->bf16 on A side) -------
// BK=64, XCD-swizzled 1D grid. A staged via reg-convert (byte-identical LDS image
// to the old gload16+preswizzle path); W staged via gload16 (bf16 from k_cvt_w).
__global__ __launch_bounds__(256) void k_proj(
    const float* __restrict__ xq, const float* __restrict__ xk, const float* __restrict__ xv,
    const __hip_bfloat16* __restrict__ wt,
    const float* __restrict__ bq, const float* __restrict__ bk, const float* __restrict__ bv,
    __hip_bfloat16* __restrict__ Qb, __hip_bfloat16* __restrict__ Kb,
    __hip_bfloat16* __restrict__ Vt) {
  __shared__ char smem[32768];
  char* As = smem;            // [128 rows][64 bf16] = 128 B rows, 16 KB
  char* Bs = smem + 16384;
  const int orig = blockIdx.x;
  const int xcd = orig & 7, idx = orig >> 3;    // idx 0..95
  const int by = xcd * 4 + (idx & 3);           // 0..31
  const int bx = (idx >> 2) & 7;                // 0..7
  const int t = idx >> 5;                       // 0..2
  const float* Xf = (t == 0) ? xq : (t == 1) ? xk : xv;
  const char* W = (const char*)(wt + (size_t)t * 1048576);
  const float* bias = (t == 0) ? bq : (t == 1) ? bk : bv;
  const int m0 = by * 128, n0 = bx * 128;
  const int tid = threadIdx.x, w = tid >> 6, lane = tid & 63;
  const int l15 = lane & 15, g = lane >> 4;
  const int l8 = lane >> 3, l7 = lane & 7;
  const int vswz = ((l7 ^ l8) << 4);            // pre-swizzled 16B slot in 128B bf16 row
  const int wm = (w >> 1) * 64, wn = (w & 1) * 64;
  f32x4 acc[4][4];
#pragma unroll
  for (int i = 0; i < 4; ++i)
#pragma unroll
    for (int j = 0; j < 4; ++j) acc[i][j] = (f32x4){0.f, 0.f, 0.f, 0.f};

  // staging pointers + prologue A-load (fp32, 2x vswz byte offset)
  const char* aptr[4];
  const char* wptr[4];
  float4 ar[4][2];
#pragma unroll
  for (int j = 0; j < 4; ++j) {
    const int ch = w * 4 + j;
    aptr[j] = (const char*)Xf + (size_t)(m0 + ch * 8 + l8) * 4096 + 2 * vswz;
    wptr[j] = W + (size_t)(n0 + ch * 8 + l8) * 2048 + vswz;
    ar[j][0] = *(const float4*)aptr[j];
    ar[j][1] = *(const float4*)(aptr[j] + 16);
    aptr[j] += 256;
  }

  for (int s = 0; s < 16; ++s) {              // 16 K-steps of 64 elems
    __syncthreads();                          // smem free
#pragma unroll
    for (int j = 0; j < 4; ++j) {
      const int ch = w * 4 + j;
      gload16(wptr[j], Bs + ch * 1024);
      wptr[j] += 128;
    }
#pragma unroll
    for (int j = 0; j < 4; ++j) {             // convert + write A (waits A loads)
      const int ch = w * 4 + j;
      union { short8 s8; __hip_bfloat16 h[8]; } u;
      u.h[0] = __float2bfloat16(ar[j][0].x); u.h[1] = __float2bfloat16(ar[j][0].y);
      u.h[2] = __float2bfloat16(ar[j][0].z); u.h[3] = __float2bfloat16(ar[j][0].w);
      u.h[4] = __float2bfloat16(ar[j][1].x); u.h[5] = __float2bfloat16(ar[j][1].y);
      u.h[6] = __float2bfloat16(ar[j][1].z); u.h[7] = __float2bfloat16(ar[j][1].w);
      *(short8*)(As + ch * 1024 + lane * 16) = u.s8;
    }
    __syncthreads();                          // tile ready (drains B gloads + writes)
    if (s < 15) {                             // next A loads overlap MFMA
#pragma unroll
      for (int j = 0; j < 4; ++j) {
        ar[j][0] = *(const float4*)aptr[j];
        ar[j][1] = *(const float4*)(aptr[j] + 16);
        aptr[j] += 256;
      }
    }
#pragma unroll
    for (int kk = 0; kk < 2; ++kk) {
      short8 af[4], bf_[4];
#pragma unroll
      for (int mt = 0; mt < 4; ++mt) {
        const int row = wm + mt * 16 + l15;
        af[mt] = *(const short8*)(As + row * 128 + ((kk * 64 + g * 16) ^ ((row & 7) << 4)));
      }
#pragma unroll
      for (int nt = 0; nt < 4; ++nt) {
        const int row = wn + nt * 16 + l15;
        bf_[nt] = *(const short8*)(Bs + row * 128 + ((kk * 64 + g * 16) ^ ((row & 7) << 4)));
      }
#pragma unroll
      for (int mt = 0; mt < 4; ++mt)
#pragma unroll
        for (int nt = 0; nt < 4; ++nt)
          acc[mt][nt] = __builtin_amdgcn_mfma_f32_16x16x32_bf16(af[mt], bf_[nt], acc[mt][nt], 0, 0, 0);
    }
  }

  float bv4[4];
#pragma unroll
  for (int nt = 0; nt < 4; ++nt) bv4[nt] = bias[n0 + wn + nt * 16 + l15];

  if (t < 2) {
    // Q/K epilogue: direct scatter (verified path)
#pragma unroll
    for (int mt = 0; mt < 4; ++mt) {
#pragma unroll
      for (int nt = 0; nt < 4; ++nt) {
        const int feat = n0 + wn + nt * 16 + l15;
        const int h = feat >> 6, d = feat & 63;
#pragma unroll
        for (int r = 0; r < 4; ++r) {
          const int token = m0 + wm + mt * 16 + g * 4 + r;
          const int b = token >> 11, s = token & 2047;
          const float val = acc[mt][nt][r] + bv4[nt];
          const __hip_bfloat16 hb = __float2bfloat16(val);
          if (t == 0) Qb[((size_t)(b * 16 + h) * 2048 + s) * 64 + d] = hb;
          else        Kb[((size_t)(b * 16 + h) * 2048 + s) * 64 + d] = hb;
        }
      }
    }
  } else {
    // V epilogue: LDS transpose -> coalesced stores, permuted keys (verified r9)
    __hip_bfloat16* T2 = (__hip_bfloat16*)smem;
    const int bb = m0 >> 11;
    const int s0 = m0 & 2047;
#pragma unroll
    for (int p = 0; p < 2; ++p) {
      __syncthreads();
      if ((w >> 1) == p) {
#pragma unroll
        for (int mt = 0; mt < 4; ++mt)
#pragma unroll
          for (int nt = 0; nt < 4; ++nt) {
            const int feat = wn + nt * 16 + l15;
#pragma unroll
            for (int r = 0; r < 4; ++r) {
              const int tok = mt * 16 + g * 4 + r;
              const int pp = ((tok >> 2) & 3) * 16 + ((tok >> 4) << 2) + (tok & 3);
              T2[feat * 64 + (pp ^ ((feat & 7) << 3))] =
                  __float2bfloat16(acc[mt][nt][r] + bv4[nt]);
            }
          }
      }
      __syncthreads();
#pragma unroll
      for (int sw = 0; sw < 4; ++sw) {
        const int row = sw * 32 + (tid >> 3);
        const int c = tid & 7;
        const short8 vchunk = *(const short8*)(smem + row * 128 + 16 * (c ^ (row & 7)));
        const int gfeat = n0 + row;
        const int hh = gfeat >> 6, dd = gfeat & 63;
        *(short8*)(Vt + ((size_t)((bb * 16 + hh) * 64 + dd)) * 2048 + s0 + p * 64 + c * 8) = vchunk;
      }
    }
  }
}

// ---------------- kernel 3: flash attention (unroll-2, static buffers) ---------
// 1024 blocks (XCD-swizzled), 4 waves x 16 q = 64 q/block, KVBLK=64.
// All r9-verified data paths; buffer index is a compile-time literal so LDS
// addresses fold into ds_read offsets; staging/mask pointers strength-reduced.
#define ATTN_BODY(CUR, NXT, PREF)                                              \
  {                                                                            \
    float4 mb[4];                                                              \
    _Pragma("unroll") for (int nt = 0; nt < 4; ++nt)                           \
        mb[nt] = *(const float4*)(mbp + nt * 16 + g * 4);                      \
    mbp += 64;                                                                 \
    if (PREF) {                                                                \
      _Pragma("unroll") for (int j = 0; j < 2; ++j) {                          \
        gload16(kst[j], Ks[NXT] + (w * 2 + j) * 1024);                         \
        gload16(vst[j], Vs[NXT] + (w * 2 + j) * 1024);                         \
      }                                                                        \
    }                                                                          \
    kst[0] += 8192; kst[1] += 8192; vst[0] += 128; vst[1] += 128;              \
    f32x4 s_[4];                                                               \
    __builtin_amdgcn_s_setprio(1);                                             \
    _Pragma("unroll") for (int nt = 0; nt < 4; ++nt) {                         \
      s_[nt] = (f32x4){0.f, 0.f, 0.f, 0.f};                                    \
      const int key = nt * 16 + l15;                                           \
      _Pragma("unroll") for (int kc = 0; kc < 2; ++kc) {                       \
        const short8 kf = *(const short8*)(Ks[CUR] + key * 128 +               \
                           ((kc * 64 + g * 16) ^ ((key & 7) << 4)));           \
        s_[nt] = __builtin_amdgcn_mfma_f32_16x16x32_bf16(kf, aq[kc], s_[nt], 0, 0, 0); \
      }                                                                        \
    }                                                                          \
    __builtin_amdgcn_s_setprio(0);                                             \
    short4v pb[4];                                                             \
    _Pragma("unroll") for (int nt = 0; nt < 4; ++nt) {                         \
      union { short4v s4; __hip_bfloat16 hh[4]; } pu;                          \
      pu.hh[0] = __float2bfloat16(EXP2F(fmaf(s_[nt][0], SC_L2E, mb[nt].x)));   \
      pu.hh[1] = __float2bfloat16(EXP2F(fmaf(s_[nt][1], SC_L2E, mb[nt].y)));   \
      pu.hh[2] = __float2bfloat16(EXP2F(fmaf(s_[nt][2], SC_L2E, mb[nt].z)));   \
      pu.hh[3] = __float2bfloat16(EXP2F(fmaf(s_[nt][3], SC_L2E, mb[nt].w)));   \
      pb[nt] = pu.s4;                                                          \
    }                                                                          \
    __builtin_amdgcn_s_setprio(1);                                             \
    _Pragma("unroll") for (int nt = 0; nt < 4; ++nt)                           \
        lacc = mfma16(ones4, pb[nt], lacc);                                    \
    _Pragma("unroll") for (int dt = 0; dt < 4; ++dt) {                         \
      const int d = dt * 16 + l15;                                             \
      const int sw2 = (d & 7) << 4;                                            \
      f32x4 o = oaccT[dt];                                                     \
      union { short8 s8; short4v h[2]; } v01, v23;                             \
      v01.s8 = *(const short8*)(Vs[CUR] + d * 128 + ((g * 32) ^ sw2));         \
      v23.s8 = *(const short8*)(Vs[CUR] + d * 128 + ((g * 32 + 16) ^ sw2));    \
      o = mfma16(v01.h[0], pb[0], o);                                          \
      o = mfma16(v01.h[1], pb[1], o);                                          \
      o = mfma16(v23.h[0], pb[2], o);                                          \
      o = mfma16(v23.h[1], pb[3], o);                                          \
      oaccT[dt] = o;                                                           \
    }                                                                          \
    __builtin_amdgcn_s_setprio(0);                                             \
    __syncthreads();                                                           \
  }

__global__ __launch_bounds__(256, 4) void k_attn(
    const __hip_bfloat16* __restrict__ Qb, const __hip_bfloat16* __restrict__ Kb,
    const __hip_bfloat16* __restrict__ Vt, const float* __restrict__ bias2,
    float* __restrict__ out) {
  __shared__ char Ks[2][8192];              // [64 keys][64 d] bf16, 128B rows, swizzled
  __shared__ char Vs[2][8192];              // [64 d][64 key-slots] bf16, swizzled
  const int orig = blockIdx.x;
  const int swz = (orig & 7) * 128 + (orig >> 3);  // bijective; 4 heads per XCD
  const int bh = swz >> 5, qb = swz & 31;
  const int b = bh >> 4, h = bh & 15;
  const int tid = threadIdx.x, w = tid >> 6, lane = tid & 63;
  const int g = lane >> 4, l15 = lane & 15;
  const char* Qc = (const char*)(Qb + (size_t)bh * 131072);
  const char* Kc = (const char*)(Kb + (size_t)bh * 131072);
  const char* Vc = (const char*)(Vt + (size_t)bh * 131072);

  const int l8 = lane >> 3, l7 = lane & 7;
  const int vswz = ((l7 ^ l8) << 4);        // pre-swizzled global 16B slot in 128B row

  // Q B-fragments: lane holds Q[q=l15][k = kc*32 + g*8 .. +7]
  short8 aq[2];
  const int arow = qb * 64 + w * 16 + l15;
#pragma unroll
  for (int kc = 0; kc < 2; ++kc)
    aq[kc] = *(const short8*)(Qc + (size_t)arow * 128 + kc * 64 + g * 16);

  f32x4 oaccT[4];                           // O^T: row d=dt*16+g*4+r, col q=l15
#pragma unroll
  for (int i = 0; i < 4; ++i) oaccT[i] = (f32x4){0.f, 0.f, 0.f, 0.f};
  f32x4 lacc = (f32x4){0.f, 0.f, 0.f, 0.f};   // denominator via ones-MFMA
  const short4v ones4 = {(short)0x3F80, (short)0x3F80, (short)0x3F80, (short)0x3F80};

  // prologue: stage tile 0 into buffer 0; init running staging pointers
  const char* kst[2];
  const char* vst[2];
#pragma unroll
  for (int j = 0; j < 2; ++j) {
    const int ch = w * 2 + j;
    kst[j] = Kc + (size_t)(ch * 8 + l8) * 128 + vswz;
    vst[j] = Vc + (size_t)(ch * 8 + l8) * 4096 + vswz;
    gload16(kst[j], Ks[0] + ch * 1024);
    gload16(vst[j], Vs[0] + ch * 1024);
    kst[j] += 8192;
    vst[j] += 128;
  }
  __syncthreads();

  const float* mbp = bias2 + b * 2048;
  for (int kt = 0; kt < 32; kt += 2) {
    ATTN_BODY(0, 1, true)
    ATTN_BODY(1, 0, (kt + 1 < 31))
  }

  // epilogue: lacc rows all equal the full denominator for this lane's q
  const float rl = 1.0f / lacc[0];
  float* orow = out + ((size_t)(b * 2048 + arow)) * 1024 + h * 64;
#pragma unroll
  for (int dt = 0; dt < 4; ++dt) {
    float4 st;
    st.x = oaccT[dt][0] * rl; st.y = oaccT[dt][1] * rl;
    st.z = oaccT[dt][2] * rl; st.w = oaccT[dt][3] * rl;
    *(float4*)(orow + dt * 16 + g * 4) = st;
  }
}

// ---------------- launcher ----------------
extern "C" void kernel_launch(void* const* d_in, const int* in_sizes, int n_in,
                              void* d_out, int out_size, void* d_ws, size_t ws_size,
                              hipStream_t stream) {
  const float* q   = (const float*)d_in[0];
  const float* k   = (const float*)d_in[1];
  const float* v   = (const float*)d_in[2];
  const int* mask  = (const int*)d_in[3];
  const float* Wq  = (const float*)d_in[4];
  const float* bq  = (const float*)d_in[5];
  const float* Wk  = (const float*)d_in[6];
  const float* bk  = (const float*)d_in[7];
  const float* Wv  = (const float*)d_in[8];
  const float* bv  = (const float*)d_in[9];
  float* out = (float*)d_out;
  char* ws = (char*)d_ws;
  __hip_bfloat16* Wt = (__hip_bfloat16*)(ws + 25165824);
  __hip_bfloat16* Qb = (__hip_bfloat16*)(ws + 31457280);
  __hip_bfloat16* Kb = (__hip_bfloat16*)(ws + 39845888);
  __hip_bfloat16* Vt = (__hip_bfloat16*)(ws + 48234496);
  float* bias2      = (float*)(ws + 56623104);   // 4096 floats

  k_cvt_w<<<dim3(16, 16, 3), dim3(256), 0, stream>>>(Wq, Wk, Wv, Wt, mask, bias2);
  k_proj<<<dim3(768), dim3(256), 0, stream>>>(q, k, v, Wt, bq, bk, bv, Qb, Kb, Vt);
  k_attn<<<dim3(1024), dim3(256), 0, stream>>>(Qb, Kb, Vt, bias2, out);
}

// Round 11
// 115.278 us; speedup vs baseline: 1.1877x; 1.1877x over previous
//
#include <hip/hip_runtime.h>
#include <hip/hip_bf16.h>

typedef __attribute__((ext_vector_type(8))) short short8;
typedef __attribute__((ext_vector_type(4))) short short4v;
typedef __attribute__((ext_vector_type(4))) float f32x4;

#define SC_L2E 0.4561727848849353f          // (1/sqrt(10)) * log2(e)

#if __has_builtin(__builtin_amdgcn_exp2f)
#define EXP2F __builtin_amdgcn_exp2f
#else
#define EXP2F exp2f
#endif

static __device__ __forceinline__ f32x4 mfma16(short4v a, short4v b, f32x4 c) {
#if __has_builtin(__builtin_amdgcn_mfma_f32_16x16x16bf16_1k)
  return __builtin_amdgcn_mfma_f32_16x16x16bf16_1k(a, b, c, 0, 0, 0);
#else
  asm("v_mfma_f32_16x16x16_bf16 %0, %1, %2, %0" : "+v"(c) : "v"(a), "v"(b));
  return c;
#endif
}

static __device__ __forceinline__ void gload16(const void* g, void* l) {
  __builtin_amdgcn_global_load_lds((const __attribute__((address_space(1))) void*)g,
                                   (__attribute__((address_space(3))) void*)l, 16, 0, 0);
}

// ---------------- kernel 1: fused converts (r9-verified) ----------------
// blocks 0..6143: q,k,v fp32->bf16 (8 elems/thread).
// blocks 6144..6911: weight transpose W^T bf16 (+ mask bias fill).
__global__ void k_cvt(const float* __restrict__ q, const float* __restrict__ kk,
                      const float* __restrict__ v, __hip_bfloat16* __restrict__ xb,
                      const float* __restrict__ Wq, const float* __restrict__ Wk,
                      const float* __restrict__ Wv, __hip_bfloat16* __restrict__ wt,
                      const int* __restrict__ mask, float* __restrict__ bias2) {
  __shared__ float T[64][65];
  if (blockIdx.x < 6144) {
    const size_t i = ((size_t)blockIdx.x * 256 + threadIdx.x) * 8;
    const int t = (int)(i >> 22);               // 4194304 elements per tensor
    const float* src = (t == 0) ? q : (t == 1) ? kk : v;
    const size_t off = i & 4194303u;
    float4 f0 = *(const float4*)(src + off);
    float4 f1 = *(const float4*)(src + off + 4);
    union { short8 s; __hip_bfloat16 h[8]; } u;
    u.h[0] = __float2bfloat16(f0.x); u.h[1] = __float2bfloat16(f0.y);
    u.h[2] = __float2bfloat16(f0.z); u.h[3] = __float2bfloat16(f0.w);
    u.h[4] = __float2bfloat16(f1.x); u.h[5] = __float2bfloat16(f1.y);
    u.h[6] = __float2bfloat16(f1.z); u.h[7] = __float2bfloat16(f1.w);
    *(short8*)((char*)xb + i * 2) = u.s;
    return;
  }
  const int idx2 = blockIdx.x - 6144;           // 0..767
  const int z = idx2 >> 8;                      // 0..2
  const int r2 = idx2 & 255;
  const int bxi = r2 & 15, byi = r2 >> 4;
  if (z == 0 && byi == 0) {
    const int idx = bxi * 256 + threadIdx.x;
    bias2[idx] = mask[idx] ? -12.0f : -1e30f;   // static shift M=12 folded in
  }
  const float* W = (z == 0) ? Wq : (z == 1) ? Wk : Wv;
  __hip_bfloat16* Wd = wt + (size_t)z * 1048576;
  const int n0 = bxi * 64, k0 = byi * 64;
  const int tx = threadIdx.x & 63, ty = threadIdx.x >> 6;
#pragma unroll
  for (int r = 0; r < 16; ++r)
    T[ty + r * 4][tx] = W[(size_t)(k0 + ty + r * 4) * 1024 + n0 + tx];
  __syncthreads();
#pragma unroll
  for (int r = 0; r < 16; ++r)
    Wd[(size_t)(n0 + ty + r * 4) * 1024 + k0 + tx] = __float2bfloat16(T[tx][ty + r * 4]);
}

// ---------------- kernel 2: projection GEMM (r9-verified; BK=64, XCD swizzle) --
__global__ __launch_bounds__(256) void k_proj(
    const __hip_bfloat16* __restrict__ xb, const __hip_bfloat16* __restrict__ wt,
    const float* __restrict__ bq, const float* __restrict__ bk, const float* __restrict__ bv,
    __hip_bfloat16* __restrict__ Qb, __hip_bfloat16* __restrict__ Kb,
    __hip_bfloat16* __restrict__ Vt) {
  __shared__ char smem[32768];
  char* As = smem;            // [128 rows][64 bf16] = 128 B rows, 16 KB
  char* Bs = smem + 16384;
  const int orig = blockIdx.x;
  const int xcd = orig & 7, idx = orig >> 3;    // idx 0..95
  const int by = xcd * 4 + (idx & 3);           // 0..31
  const int bx = (idx >> 2) & 7;                // 0..7
  const int t = idx >> 5;                       // 0..2
  const char* X = (const char*)(xb + (size_t)t * 4194304);
  const char* W = (const char*)(wt + (size_t)t * 1048576);
  const float* bias = (t == 0) ? bq : (t == 1) ? bk : bv;
  const int m0 = by * 128, n0 = bx * 128;
  const int tid = threadIdx.x, w = tid >> 6, lane = tid & 63;
  const int l15 = lane & 15, g = lane >> 4;
  const int l8 = lane >> 3, l7 = lane & 7;
  const int vswz = ((l7 ^ l8) << 4);            // pre-swizzled 16B slot in 128B row
  const int wm = (w >> 1) * 64, wn = (w & 1) * 64;
  f32x4 acc[4][4];
#pragma unroll
  for (int i = 0; i < 4; ++i)
#pragma unroll
    for (int j = 0; j < 4; ++j) acc[i][j] = (f32x4){0.f, 0.f, 0.f, 0.f};

  for (int k0 = 0; k0 < 2048; k0 += 128) {      // 16 K-steps of 64 elems
    __syncthreads();
#pragma unroll
    for (int j = 0; j < 4; ++j) {
      const int ch = w * 4 + j;                 // 16 chunks of 8 rows
      gload16(X + (size_t)(m0 + ch * 8 + l8) * 2048 + k0 + vswz, As + ch * 1024);
      gload16(W + (size_t)(n0 + ch * 8 + l8) * 2048 + k0 + vswz, Bs + ch * 1024);
    }
    __syncthreads();
#pragma unroll
    for (int kk = 0; kk < 2; ++kk) {
      short8 af[4], bf_[4];
#pragma unroll
      for (int mt = 0; mt < 4; ++mt) {
        const int row = wm + mt * 16 + l15;
        af[mt] = *(const short8*)(As + row * 128 + ((kk * 64 + g * 16) ^ ((row & 7) << 4)));
      }
#pragma unroll
      for (int nt = 0; nt < 4; ++nt) {
        const int row = wn + nt * 16 + l15;
        bf_[nt] = *(const short8*)(Bs + row * 128 + ((kk * 64 + g * 16) ^ ((row & 7) << 4)));
      }
#pragma unroll
      for (int mt = 0; mt < 4; ++mt)
#pragma unroll
        for (int nt = 0; nt < 4; ++nt)
          acc[mt][nt] = __builtin_amdgcn_mfma_f32_16x16x32_bf16(af[mt], bf_[nt], acc[mt][nt], 0, 0, 0);
    }
  }

  float bv4[4];
#pragma unroll
  for (int nt = 0; nt < 4; ++nt) bv4[nt] = bias[n0 + wn + nt * 16 + l15];

  if (t < 2) {
    // Q/K epilogue: direct scatter (verified path)
#pragma unroll
    for (int mt = 0; mt < 4; ++mt) {
#pragma unroll
      for (int nt = 0; nt < 4; ++nt) {
        const int feat = n0 + wn + nt * 16 + l15;
        const int h = feat >> 6, d = feat & 63;
#pragma unroll
        for (int r = 0; r < 4; ++r) {
          const int token = m0 + wm + mt * 16 + g * 4 + r;
          const int b = token >> 11, s = token & 2047;
          const float val = acc[mt][nt][r] + bv4[nt];
          const __hip_bfloat16 hb = __float2bfloat16(val);
          if (t == 0) Qb[((size_t)(b * 16 + h) * 2048 + s) * 64 + d] = hb;
          else        Kb[((size_t)(b * 16 + h) * 2048 + s) * 64 + d] = hb;
        }
      }
    }
  } else {
    // V epilogue: LDS transpose -> coalesced stores; keys PERMUTED within each
    // 64-token block: p = ((t>>2)&3)*16 + (t>>4)*4 + (t&3) (r9-verified).
    __hip_bfloat16* T2 = (__hip_bfloat16*)smem;
    const int bb = m0 >> 11;
    const int s0 = m0 & 2047;
#pragma unroll
    for (int p = 0; p < 2; ++p) {
      __syncthreads();
      if ((w >> 1) == p) {
#pragma unroll
        for (int mt = 0; mt < 4; ++mt)
#pragma unroll
          for (int nt = 0; nt < 4; ++nt) {
            const int feat = wn + nt * 16 + l15;
#pragma unroll
            for (int r = 0; r < 4; ++r) {
              const int tok = mt * 16 + g * 4 + r;
              const int pp = ((tok >> 2) & 3) * 16 + ((tok >> 4) << 2) + (tok & 3);
              T2[feat * 64 + (pp ^ ((feat & 7) << 3))] =
                  __float2bfloat16(acc[mt][nt][r] + bv4[nt]);
            }
          }
      }
      __syncthreads();
#pragma unroll
      for (int sw = 0; sw < 4; ++sw) {
        const int row = sw * 32 + (tid >> 3);
        const int c = tid & 7;
        const short8 vchunk = *(const short8*)(smem + row * 128 + 16 * (c ^ (row & 7)));
        const int gfeat = n0 + row;
        const int hh = gfeat >> 6, dd = gfeat & 63;
        *(short8*)(Vt + ((size_t)((bb * 16 + hh) * 64 + dd)) * 2048 + s0 + p * 64 + c * 8) = vchunk;
      }
    }
  }
}

// ---------------- kernel 3: flash attention (r10-verified unroll-2) ------------
#define ATTN_BODY(CUR, NXT, PREF)                                              \
  {                                                                            \
    float4 mb[4];                                                              \
    _Pragma("unroll") for (int nt = 0; nt < 4; ++nt)                           \
        mb[nt] = *(const float4*)(mbp + nt * 16 + g * 4);                      \
    mbp += 64;                                                                 \
    if (PREF) {                                                                \
      _Pragma("unroll") for (int j = 0; j < 2; ++j) {                          \
        gload16(kst[j], Ks[NXT] + (w * 2 + j) * 1024);                         \
        gload16(vst[j], Vs[NXT] + (w * 2 + j) * 1024);                         \
      }                                                                        \
    }                                                                          \
    kst[0] += 8192; kst[1] += 8192; vst[0] += 128; vst[1] += 128;              \
    f32x4 s_[4];                                                               \
    __builtin_amdgcn_s_setprio(1);                                             \
    _Pragma("unroll") for (int nt = 0; nt < 4; ++nt) {                         \
      s_[nt] = (f32x4){0.f, 0.f, 0.f, 0.f};                                    \
      const int key = nt * 16 + l15;                                           \
      _Pragma("unroll") for (int kc = 0; kc < 2; ++kc) {                       \
        const short8 kf = *(const short8*)(Ks[CUR] + key * 128 +               \
                           ((kc * 64 + g * 16) ^ ((key & 7) << 4)));           \
        s_[nt] = __builtin_amdgcn_mfma_f32_16x16x32_bf16(kf, aq[kc], s_[nt], 0, 0, 0); \
      }                                                                        \
    }                                                                          \
    __builtin_amdgcn_s_setprio(0);                                             \
    short4v pb[4];                                                             \
    _Pragma("unroll") for (int nt = 0; nt < 4; ++nt) {                         \
      union { short4v s4; __hip_bfloat16 hh[4]; } pu;                          \
      pu.hh[0] = __float2bfloat16(EXP2F(fmaf(s_[nt][0], SC_L2E, mb[nt].x)));   \
      pu.hh[1] = __float2bfloat16(EXP2F(fmaf(s_[nt][1], SC_L2E, mb[nt].y)));   \
      pu.hh[2] = __float2bfloat16(EXP2F(fmaf(s_[nt][2], SC_L2E, mb[nt].z)));   \
      pu.hh[3] = __float2bfloat16(EXP2F(fmaf(s_[nt][3], SC_L2E, mb[nt].w)));   \
      pb[nt] = pu.s4;                                                          \
    }                                                                          \
    __builtin_amdgcn_s_setprio(1);                                             \
    _Pragma("unroll") for (int nt = 0; nt < 4; ++nt)                           \
        lacc = mfma16(ones4, pb[nt], lacc);                                    \
    _Pragma("unroll") for (int dt = 0; dt < 4; ++dt) {                         \
      const int d = dt * 16 + l15;                                             \
      const int sw2 = (d & 7) << 4;                                            \
      f32x4 o = oaccT[dt];                                                     \
      union { short8 s8; short4v h[2]; } v01, v23;                             \
      v01.s8 = *(const short8*)(Vs[CUR] + d * 128 + ((g * 32) ^ sw2));         \
      v23.s8 = *(const short8*)(Vs[CUR] + d * 128 + ((g * 32 + 16) ^ sw2));    \
      o = mfma16(v01.h[0], pb[0], o);                                          \
      o = mfma16(v01.h[1], pb[1], o);                                          \
      o = mfma16(v23.h[0], pb[2], o);                                          \
      o = mfma16(v23.h[1], pb[3], o);                                          \
      oaccT[dt] = o;                                                           \
    }                                                                          \
    __builtin_amdgcn_s_setprio(0);                                             \
    __syncthreads();                                                           \
  }

__global__ __launch_bounds__(256, 4) void k_attn(
    const __hip_bfloat16* __restrict__ Qb, const __hip_bfloat16* __restrict__ Kb,
    const __hip_bfloat16* __restrict__ Vt, const float* __restrict__ bias2,
    float* __restrict__ out) {
  __shared__ char Ks[2][8192];              // [64 keys][64 d] bf16, 128B rows, swizzled
  __shared__ char Vs[2][8192];              // [64 d][64 key-slots] bf16, swizzled
  const int orig = blockIdx.x;
  const int swz = (orig & 7) * 128 + (orig >> 3);  // bijective; 4 heads per XCD
  const int bh = swz >> 5, qb = swz & 31;
  const int b = bh >> 4, h = bh & 15;
  const int tid = threadIdx.x, w = tid >> 6, lane = tid & 63;
  const int g = lane >> 4, l15 = lane & 15;
  const char* Qc = (const char*)(Qb + (size_t)bh * 131072);
  const char* Kc = (const char*)(Kb + (size_t)bh * 131072);
  const char* Vc = (const char*)(Vt + (size_t)bh * 131072);

  const int l8 = lane >> 3, l7 = lane & 7;
  const int vswz = ((l7 ^ l8) << 4);        // pre-swizzled global 16B slot in 128B row

  // Q B-fragments: lane holds Q[q=l15][k = kc*32 + g*8 .. +7]
  short8 aq[2];
  const int arow = qb * 64 + w * 16 + l15;
#pragma unroll
  for (int kc = 0; kc < 2; ++kc)
    aq[kc] = *(const short8*)(Qc + (size_t)arow * 128 + kc * 64 + g * 16);

  f32x4 oaccT[4];                           // O^T: row d=dt*16+g*4+r, col q=l15
#pragma unroll
  for (int i = 0; i < 4; ++i) oaccT[i] = (f32x4){0.f, 0.f, 0.f, 0.f};
  f32x4 lacc = (f32x4){0.f, 0.f, 0.f, 0.f};   // denominator via ones-MFMA
  const short4v ones4 = {(short)0x3F80, (short)0x3F80, (short)0x3F80, (short)0x3F80};

  // prologue: stage tile 0 into buffer 0; init running staging pointers
  const char* kst[2];
  const char* vst[2];
#pragma unroll
  for (int j = 0; j < 2; ++j) {
    const int ch = w * 2 + j;
    kst[j] = Kc + (size_t)(ch * 8 + l8) * 128 + vswz;
    vst[j] = Vc + (size_t)(ch * 8 + l8) * 4096 + vswz;
    gload16(kst[j], Ks[0] + ch * 1024);
    gload16(vst[j], Vs[0] + ch * 1024);
    kst[j] += 8192;
    vst[j] += 128;
  }
  __syncthreads();

  const float* mbp = bias2 + b * 2048;
  for (int kt = 0; kt < 32; kt += 2) {
    ATTN_BODY(0, 1, true)
    ATTN_BODY(1, 0, (kt + 1 < 31))
  }

  // epilogue: lacc rows all equal the full denominator for this lane's q
  const float rl = 1.0f / lacc[0];
  float* orow = out + ((size_t)(b * 2048 + arow)) * 1024 + h * 64;
#pragma unroll
  for (int dt = 0; dt < 4; ++dt) {
    float4 st;
    st.x = oaccT[dt][0] * rl; st.y = oaccT[dt][1] * rl;
    st.z = oaccT[dt][2] * rl; st.w = oaccT[dt][3] * rl;
    *(float4*)(orow + dt * 16 + g * 4) = st;
  }
}

// ---------------- launcher ----------------
extern "C" void kernel_launch(void* const* d_in, const int* in_sizes, int n_in,
                              void* d_out, int out_size, void* d_ws, size_t ws_size,
                              hipStream_t stream) {
  const float* q   = (const float*)d_in[0];
  const float* k   = (const float*)d_in[1];
  const float* v   = (const float*)d_in[2];
  const int* mask  = (const int*)d_in[3];
  const float* Wq  = (const float*)d_in[4];
  const float* bq  = (const float*)d_in[5];
  const float* Wk  = (const float*)d_in[6];
  const float* bk  = (const float*)d_in[7];
  const float* Wv  = (const float*)d_in[8];
  const float* bv  = (const float*)d_in[9];
  float* out = (float*)d_out;
  char* ws = (char*)d_ws;
  __hip_bfloat16* Xb = (__hip_bfloat16*)(ws);
  __hip_bfloat16* Wt = (__hip_bfloat16*)(ws + 25165824);
  __hip_bfloat16* Qb = (__hip_bfloat16*)(ws + 31457280);
  __hip_bfloat16* Kb = (__hip_bfloat16*)(ws + 39845888);
  __hip_bfloat16* Vt = (__hip_bfloat16*)(ws + 48234496);
  float* bias2      = (float*)(ws + 56623104);   // 4096 floats

  k_cvt<<<dim3(6912), dim3(256), 0, stream>>>(q, k, v, Xb, Wq, Wk, Wv, Wt, mask, bias2);
  k_proj<<<dim3(768), dim3(256), 0, stream>>>(Xb, Wt, bq, bk, bv, Qb, Kb, Vt);
  k_attn<<<dim3(1024), dim3(256), 0, stream>>>(Qb, Kb, Vt, bias2, out);
}

// Round 12
// 109.821 us; speedup vs baseline: 1.2468x; 1.0497x over previous
//
#include <hip/hip_runtime.h>
#include <hip/hip_bf16.h>

typedef __attribute__((ext_vector_type(8))) short short8;
typedef __attribute__((ext_vector_type(4))) float f32x4;

#define SC_L2E 0.4561727848849353f          // (1/sqrt(10)) * log2(e)

#if __has_builtin(__builtin_amdgcn_exp2f)
#define EXP2F __builtin_amdgcn_exp2f
#else
#define EXP2F exp2f
#endif

static __device__ __forceinline__ void gload16(const void* g, void* l) {
  __builtin_amdgcn_global_load_lds((const __attribute__((address_space(1))) void*)g,
                                   (__attribute__((address_space(3))) void*)l, 16, 0, 0);
}

// ---------------- kernel 1: fused converts (r9-verified) ----------------
__global__ void k_cvt(const float* __restrict__ q, const float* __restrict__ kk,
                      const float* __restrict__ v, __hip_bfloat16* __restrict__ xb,
                      const float* __restrict__ Wq, const float* __restrict__ Wk,
                      const float* __restrict__ Wv, __hip_bfloat16* __restrict__ wt,
                      const int* __restrict__ mask, float* __restrict__ bias2) {
  __shared__ float T[64][65];
  if (blockIdx.x < 6144) {
    const size_t i = ((size_t)blockIdx.x * 256 + threadIdx.x) * 8;
    const int t = (int)(i >> 22);               // 4194304 elements per tensor
    const float* src = (t == 0) ? q : (t == 1) ? kk : v;
    const size_t off = i & 4194303u;
    float4 f0 = *(const float4*)(src + off);
    float4 f1 = *(const float4*)(src + off + 4);
    union { short8 s; __hip_bfloat16 h[8]; } u;
    u.h[0] = __float2bfloat16(f0.x); u.h[1] = __float2bfloat16(f0.y);
    u.h[2] = __float2bfloat16(f0.z); u.h[3] = __float2bfloat16(f0.w);
    u.h[4] = __float2bfloat16(f1.x); u.h[5] = __float2bfloat16(f1.y);
    u.h[6] = __float2bfloat16(f1.z); u.h[7] = __float2bfloat16(f1.w);
    *(short8*)((char*)xb + i * 2) = u.s;
    return;
  }
  const int idx2 = blockIdx.x - 6144;           // 0..767
  const int z = idx2 >> 8;                      // 0..2
  const int r2 = idx2 & 255;
  const int bxi = r2 & 15, byi = r2 >> 4;
  if (z == 0 && byi == 0) {
    const int idx = bxi * 256 + threadIdx.x;
    bias2[idx] = mask[idx] ? -12.0f : -1e30f;   // static shift M=12 folded in
  }
  const float* W = (z == 0) ? Wq : (z == 1) ? Wk : Wv;
  __hip_bfloat16* Wd = wt + (size_t)z * 1048576;
  const int n0 = bxi * 64, k0 = byi * 64;
  const int tx = threadIdx.x & 63, ty = threadIdx.x >> 6;
#pragma unroll
  for (int r = 0; r < 16; ++r)
    T[ty + r * 4][tx] = W[(size_t)(k0 + ty + r * 4) * 1024 + n0 + tx];
  __syncthreads();
#pragma unroll
  for (int r = 0; r < 16; ++r)
    Wd[(size_t)(n0 + ty + r * 4) * 1024 + k0 + tx] = __float2bfloat16(T[tx][ty + r * 4]);
}

// ---------------- kernel 2: projection GEMM (r9 core; V epilogue = r7 natural) -
__global__ __launch_bounds__(256) void k_proj(
    const __hip_bfloat16* __restrict__ xb, const __hip_bfloat16* __restrict__ wt,
    const float* __restrict__ bq, const float* __restrict__ bk, const float* __restrict__ bv,
    __hip_bfloat16* __restrict__ Qb, __hip_bfloat16* __restrict__ Kb,
    __hip_bfloat16* __restrict__ Vt) {
  __shared__ char smem[32768];
  char* As = smem;            // [128 rows][64 bf16] = 128 B rows, 16 KB
  char* Bs = smem + 16384;
  const int orig = blockIdx.x;
  const int xcd = orig & 7, idx = orig >> 3;    // idx 0..95
  const int by = xcd * 4 + (idx & 3);           // 0..31
  const int bx = (idx >> 2) & 7;                // 0..7
  const int t = idx >> 5;                       // 0..2
  const char* X = (const char*)(xb + (size_t)t * 4194304);
  const char* W = (const char*)(wt + (size_t)t * 1048576);
  const float* bias = (t == 0) ? bq : (t == 1) ? bk : bv;
  const int m0 = by * 128, n0 = bx * 128;
  const int tid = threadIdx.x, w = tid >> 6, lane = tid & 63;
  const int l15 = lane & 15, g = lane >> 4;
  const int l8 = lane >> 3, l7 = lane & 7;
  const int vswz = ((l7 ^ l8) << 4);            // pre-swizzled 16B slot in 128B row
  const int wm = (w >> 1) * 64, wn = (w & 1) * 64;
  f32x4 acc[4][4];
#pragma unroll
  for (int i = 0; i < 4; ++i)
#pragma unroll
    for (int j = 0; j < 4; ++j) acc[i][j] = (f32x4){0.f, 0.f, 0.f, 0.f};

  for (int k0 = 0; k0 < 2048; k0 += 128) {      // 16 K-steps of 64 elems
    __syncthreads();
#pragma unroll
    for (int j = 0; j < 4; ++j) {
      const int ch = w * 4 + j;                 // 16 chunks of 8 rows
      gload16(X + (size_t)(m0 + ch * 8 + l8) * 2048 + k0 + vswz, As + ch * 1024);
      gload16(W + (size_t)(n0 + ch * 8 + l8) * 2048 + k0 + vswz, Bs + ch * 1024);
    }
    __syncthreads();
#pragma unroll
    for (int kk = 0; kk < 2; ++kk) {
      short8 af[4], bf_[4];
#pragma unroll
      for (int mt = 0; mt < 4; ++mt) {
        const int row = wm + mt * 16 + l15;
        af[mt] = *(const short8*)(As + row * 128 + ((kk * 64 + g * 16) ^ ((row & 7) << 4)));
      }
#pragma unroll
      for (int nt = 0; nt < 4; ++nt) {
        const int row = wn + nt * 16 + l15;
        bf_[nt] = *(const short8*)(Bs + row * 128 + ((kk * 64 + g * 16) ^ ((row & 7) << 4)));
      }
#pragma unroll
      for (int mt = 0; mt < 4; ++mt)
#pragma unroll
        for (int nt = 0; nt < 4; ++nt)
          acc[mt][nt] = __builtin_amdgcn_mfma_f32_16x16x32_bf16(af[mt], bf_[nt], acc[mt][nt], 0, 0, 0);
    }
  }

  float bv4[4];
#pragma unroll
  for (int nt = 0; nt < 4; ++nt) bv4[nt] = bias[n0 + wn + nt * 16 + l15];

  if (t < 2) {
    // Q/K epilogue: direct scatter (verified path)
#pragma unroll
    for (int mt = 0; mt < 4; ++mt) {
#pragma unroll
      for (int nt = 0; nt < 4; ++nt) {
        const int feat = n0 + wn + nt * 16 + l15;
        const int h = feat >> 6, d = feat & 63;
#pragma unroll
        for (int r = 0; r < 4; ++r) {
          const int token = m0 + wm + mt * 16 + g * 4 + r;
          const int b = token >> 11, s = token & 2047;
          const float val = acc[mt][nt][r] + bv4[nt];
          const __hip_bfloat16 hb = __float2bfloat16(val);
          if (t == 0) Qb[((size_t)(b * 16 + h) * 2048 + s) * 64 + d] = hb;
          else        Kb[((size_t)(b * 16 + h) * 2048 + s) * 64 + d] = hb;
        }
      }
    }
  } else {
    // V epilogue: LDS transpose -> coalesced stores, NATURAL key order (r7-verified)
    __hip_bfloat16* T2 = (__hip_bfloat16*)smem;
    const int bb = m0 >> 11;
    const int s0 = m0 & 2047;
#pragma unroll
    for (int p = 0; p < 2; ++p) {
      __syncthreads();
      if ((w >> 1) == p) {
#pragma unroll
        for (int mt = 0; mt < 4; ++mt)
#pragma unroll
          for (int nt = 0; nt < 4; ++nt) {
            const int feat = wn + nt * 16 + l15;
#pragma unroll
            for (int r = 0; r < 4; ++r) {
              const int tok = mt * 16 + g * 4 + r;
              T2[feat * 64 + (tok ^ ((feat & 7) << 3))] =
                  __float2bfloat16(acc[mt][nt][r] + bv4[nt]);
            }
          }
      }
      __syncthreads();
#pragma unroll
      for (int sw = 0; sw < 4; ++sw) {
        const int row = sw * 32 + (tid >> 3);
        const int c = tid & 7;
        const short8 vchunk = *(const short8*)(smem + row * 128 + 16 * (c ^ (row & 7)));
        const int gfeat = n0 + row;
        const int hh = gfeat >> 6, dd = gfeat & 63;
        *(short8*)(Vt + ((size_t)((bb * 16 + hh) * 64 + dd)) * 2048 + s0 + p * 64 + c * 8) = vchunk;
      }
    }
  }
}

// ---------------- kernel 3: flash attention (all-K=32 MFMA via key permutation) -
// K staged with slot s holding actual key kappa(s) = (nt>>1)*32 + g*8 + (nt&1)*4 + r
// (s = nt*16 + g*4 + r). QK^T C/D slot s -> score(kappa(s)); lane g then holds
// exactly keys g*8..g*8+7 of each 32-key chunk -> P packs straight into K=32
// B-fragments. V natural order, read with the verified A-frag pattern.
#define ATTN_BODY(CUR, NXT, PREF)                                              \
  {                                                                            \
    float4 mb[4];                                                              \
    _Pragma("unroll") for (int nt = 0; nt < 4; ++nt)                           \
        mb[nt] = *(const float4*)(mbp + (nt >> 1) * 32 + ((nt & 1) << 2) + g * 8); \
    mbp += 64;                                                                 \
    if (PREF) {                                                                \
      _Pragma("unroll") for (int j = 0; j < 2; ++j) {                          \
        gload16(kst[j], Ks[NXT] + (w * 2 + j) * 1024);                         \
        gload16(vst[j], Vs[NXT] + (w * 2 + j) * 1024);                         \
      }                                                                        \
    }                                                                          \
    kst[0] += 8192; kst[1] += 8192; vst[0] += 128; vst[1] += 128;              \
    f32x4 s_[4];                                                               \
    __builtin_amdgcn_s_setprio(1);                                             \
    _Pragma("unroll") for (int nt = 0; nt < 4; ++nt) {                         \
      s_[nt] = (f32x4){0.f, 0.f, 0.f, 0.f};                                    \
      const int key = nt * 16 + l15;                                           \
      _Pragma("unroll") for (int kc = 0; kc < 2; ++kc) {                       \
        const short8 kf = *(const short8*)(Ks[CUR] + key * 128 +               \
                           ((kc * 64 + g * 16) ^ ((key & 7) << 4)));           \
        s_[nt] = __builtin_amdgcn_mfma_f32_16x16x32_bf16(kf, aq[kc], s_[nt], 0, 0, 0); \
      }                                                                        \
    }                                                                          \
    __builtin_amdgcn_s_setprio(0);                                             \
    short8 pb8[2];                                                             \
    _Pragma("unroll") for (int c = 0; c < 2; ++c) {                            \
      union { short8 s8; __hip_bfloat16 hh[8]; } pu;                           \
      pu.hh[0] = __float2bfloat16(EXP2F(fmaf(s_[2*c][0], SC_L2E, mb[2*c].x))); \
      pu.hh[1] = __float2bfloat16(EXP2F(fmaf(s_[2*c][1], SC_L2E, mb[2*c].y))); \
      pu.hh[2] = __float2bfloat16(EXP2F(fmaf(s_[2*c][2], SC_L2E, mb[2*c].z))); \
      pu.hh[3] = __float2bfloat16(EXP2F(fmaf(s_[2*c][3], SC_L2E, mb[2*c].w))); \
      pu.hh[4] = __float2bfloat16(EXP2F(fmaf(s_[2*c+1][0], SC_L2E, mb[2*c+1].x))); \
      pu.hh[5] = __float2bfloat16(EXP2F(fmaf(s_[2*c+1][1], SC_L2E, mb[2*c+1].y))); \
      pu.hh[6] = __float2bfloat16(EXP2F(fmaf(s_[2*c+1][2], SC_L2E, mb[2*c+1].z))); \
      pu.hh[7] = __float2bfloat16(EXP2F(fmaf(s_[2*c+1][3], SC_L2E, mb[2*c+1].w))); \
      pb8[c] = pu.s8;                                                          \
    }                                                                          \
    __builtin_amdgcn_s_setprio(1);                                             \
    lacc = __builtin_amdgcn_mfma_f32_16x16x32_bf16(ones8, pb8[0], lacc, 0, 0, 0); \
    lacc = __builtin_amdgcn_mfma_f32_16x16x32_bf16(ones8, pb8[1], lacc, 0, 0, 0); \
    _Pragma("unroll") for (int dt = 0; dt < 4; ++dt) {                         \
      const int d = dt * 16 + l15;                                             \
      const int sw2 = (d & 7) << 4;                                            \
      f32x4 o = oaccT[dt];                                                     \
      const short8 v0 = *(const short8*)(Vs[CUR] + d * 128 + ((g * 16) ^ sw2)); \
      const short8 v1 = *(const short8*)(Vs[CUR] + d * 128 + ((64 + g * 16) ^ sw2)); \
      o = __builtin_amdgcn_mfma_f32_16x16x32_bf16(v0, pb8[0], o, 0, 0, 0);     \
      o = __builtin_amdgcn_mfma_f32_16x16x32_bf16(v1, pb8[1], o, 0, 0, 0);     \
      oaccT[dt] = o;                                                           \
    }                                                                          \
    __builtin_amdgcn_s_setprio(0);                                             \
    __syncthreads();                                                           \
  }

__global__ __launch_bounds__(256, 4) void k_attn(
    const __hip_bfloat16* __restrict__ Qb, const __hip_bfloat16* __restrict__ Kb,
    const __hip_bfloat16* __restrict__ Vt, const float* __restrict__ bias2,
    float* __restrict__ out) {
  __shared__ char Ks[2][8192];              // [64 key-slots][64 d] bf16, permuted keys
  __shared__ char Vs[2][8192];              // [64 d][64 keys] bf16, natural order
  const int orig = blockIdx.x;
  const int swz = (orig & 7) * 128 + (orig >> 3);  // bijective; 4 heads per XCD
  const int bh = swz >> 5, qb = swz & 31;
  const int b = bh >> 4, h = bh & 15;
  const int tid = threadIdx.x, w = tid >> 6, lane = tid & 63;
  const int g = lane >> 4, l15 = lane & 15;
  const char* Qc = (const char*)(Qb + (size_t)bh * 131072);
  const char* Kc = (const char*)(Kb + (size_t)bh * 131072);
  const char* Vc = (const char*)(Vt + (size_t)bh * 131072);

  const int l8 = lane >> 3, l7 = lane & 7;
  const int vswz = ((l7 ^ l8) << 4);        // pre-swizzled global 16B slot in 128B row

  // Q B-fragments: lane holds Q[q=l15][k = kc*32 + g*8 .. +7]
  short8 aq[2];
  const int arow = qb * 64 + w * 16 + l15;
#pragma unroll
  for (int kc = 0; kc < 2; ++kc)
    aq[kc] = *(const short8*)(Qc + (size_t)arow * 128 + kc * 64 + g * 16);

  f32x4 oaccT[4];                           // O^T: row d=dt*16+g*4+r, col q=l15
#pragma unroll
  for (int i = 0; i < 4; ++i) oaccT[i] = (f32x4){0.f, 0.f, 0.f, 0.f};
  f32x4 lacc = (f32x4){0.f, 0.f, 0.f, 0.f};   // denominator via ones-MFMA
  const short8 ones8 = {(short)0x3F80, (short)0x3F80, (short)0x3F80, (short)0x3F80,
                        (short)0x3F80, (short)0x3F80, (short)0x3F80, (short)0x3F80};

  // prologue: stage tile 0; K source rows permuted by kappa(slot)
  const char* kst[2];
  const char* vst[2];
#pragma unroll
  for (int j = 0; j < 2; ++j) {
    const int ch = w * 2 + j;
    const int s = ch * 8 + l8;                // LDS slot-row this lane fills
    const int nt = s >> 4, gg = (s >> 2) & 3, rr = s & 3;
    const int kap = (nt >> 1) * 32 + gg * 8 + ((nt & 1) << 2) + rr;  // actual key
    kst[j] = Kc + (size_t)kap * 128 + vswz;
    vst[j] = Vc + (size_t)s * 4096 + vswz;
    gload16(kst[j], Ks[0] + ch * 1024);
    gload16(vst[j], Vs[0] + ch * 1024);
    kst[j] += 8192;
    vst[j] += 128;
  }
  __syncthreads();

  const float* mbp = bias2 + b * 2048;
  for (int kt = 0; kt < 32; kt += 2) {
    ATTN_BODY(0, 1, true)
    ATTN_BODY(1, 0, (kt + 1 < 31))
  }

  // epilogue: lacc rows all equal the full denominator for this lane's q
  const float rl = 1.0f / lacc[0];
  float* orow = out + ((size_t)(b * 2048 + arow)) * 1024 + h * 64;
#pragma unroll
  for (int dt = 0; dt < 4; ++dt) {
    float4 st;
    st.x = oaccT[dt][0] * rl; st.y = oaccT[dt][1] * rl;
    st.z = oaccT[dt][2] * rl; st.w = oaccT[dt][3] * rl;
    *(float4*)(orow + dt * 16 + g * 4) = st;
  }
}

// ---------------- launcher ----------------
extern "C" void kernel_launch(void* const* d_in, const int* in_sizes, int n_in,
                              void* d_out, int out_size, void* d_ws, size_t ws_size,
                              hipStream_t stream) {
  const float* q   = (const float*)d_in[0];
  const float* k   = (const float*)d_in[1];
  const float* v   = (const float*)d_in[2];
  const int* mask  = (const int*)d_in[3];
  const float* Wq  = (const float*)d_in[4];
  const float* bq  = (const float*)d_in[5];
  const float* Wk  = (const float*)d_in[6];
  const float* bk  = (const float*)d_in[7];
  const float* Wv  = (const float*)d_in[8];
  const float* bv  = (const float*)d_in[9];
  float* out = (float*)d_out;
  char* ws = (char*)d_ws;
  __hip_bfloat16* Xb = (__hip_bfloat16*)(ws);
  __hip_bfloat16* Wt = (__hip_bfloat16*)(ws + 25165824);
  __hip_bfloat16* Qb = (__hip_bfloat16*)(ws + 31457280);
  __hip_bfloat16* Kb = (__hip_bfloat16*)(ws + 39845888);
  __hip_bfloat16* Vt = (__hip_bfloat16*)(ws + 48234496);
  float* bias2      = (float*)(ws + 56623104);   // 4096 floats

  k_cvt<<<dim3(6912), dim3(256), 0, stream>>>(q, k, v, Xb, Wq, Wk, Wv, Wt, mask, bias2);
  k_proj<<<dim3(768), dim3(256), 0, stream>>>(Xb, Wt, bq, bk, bv, Qb, Kb, Vt);
  k_attn<<<dim3(1024), dim3(256), 0, stream>>>(Qb, Kb, Vt, bias2, out);
}

// Round 13
// 104.357 us; speedup vs baseline: 1.3120x; 1.0524x over previous
//
#include <hip/hip_runtime.h>
#include <hip/hip_bf16.h>

typedef __attribute__((ext_vector_type(8))) short short8;
typedef __attribute__((ext_vector_type(4))) float f32x4;

#define SC_L2E 0.4561727848849353f          // (1/sqrt(10)) * log2(e)

#if __has_builtin(__builtin_amdgcn_exp2f)
#define EXP2F __builtin_amdgcn_exp2f
#else
#define EXP2F exp2f
#endif

static __device__ __forceinline__ void gload16(const void* g, void* l) {
  __builtin_amdgcn_global_load_lds((const __attribute__((address_space(1))) void*)g,
                                   (__attribute__((address_space(3))) void*)l, 16, 0, 0);
}

// ---------------- kernel 1: fused converts (r9-verified) ----------------
__global__ void k_cvt(const float* __restrict__ q, const float* __restrict__ kk,
                      const float* __restrict__ v, __hip_bfloat16* __restrict__ xb,
                      const float* __restrict__ Wq, const float* __restrict__ Wk,
                      const float* __restrict__ Wv, __hip_bfloat16* __restrict__ wt,
                      const int* __restrict__ mask, float* __restrict__ bias2) {
  __shared__ float T[64][65];
  if (blockIdx.x < 6144) {
    const size_t i = ((size_t)blockIdx.x * 256 + threadIdx.x) * 8;
    const int t = (int)(i >> 22);               // 4194304 elements per tensor
    const float* src = (t == 0) ? q : (t == 1) ? kk : v;
    const size_t off = i & 4194303u;
    float4 f0 = *(const float4*)(src + off);
    float4 f1 = *(const float4*)(src + off + 4);
    union { short8 s; __hip_bfloat16 h[8]; } u;
    u.h[0] = __float2bfloat16(f0.x); u.h[1] = __float2bfloat16(f0.y);
    u.h[2] = __float2bfloat16(f0.z); u.h[3] = __float2bfloat16(f0.w);
    u.h[4] = __float2bfloat16(f1.x); u.h[5] = __float2bfloat16(f1.y);
    u.h[6] = __float2bfloat16(f1.z); u.h[7] = __float2bfloat16(f1.w);
    *(short8*)((char*)xb + i * 2) = u.s;
    return;
  }
  const int idx2 = blockIdx.x - 6144;           // 0..767
  const int z = idx2 >> 8;                      // 0..2
  const int r2 = idx2 & 255;
  const int bxi = r2 & 15, byi = r2 >> 4;
  if (z == 0 && byi == 0) {
    const int idx = bxi * 256 + threadIdx.x;
    bias2[idx] = mask[idx] ? -12.0f : -1e30f;   // static shift M=12 folded in
  }
  const float* W = (z == 0) ? Wq : (z == 1) ? Wk : Wv;
  __hip_bfloat16* Wd = wt + (size_t)z * 1048576;
  const int n0 = bxi * 64, k0 = byi * 64;
  const int tx = threadIdx.x & 63, ty = threadIdx.x >> 6;
#pragma unroll
  for (int r = 0; r < 16; ++r)
    T[ty + r * 4][tx] = W[(size_t)(k0 + ty + r * 4) * 1024 + n0 + tx];
  __syncthreads();
#pragma unroll
  for (int r = 0; r < 16; ++r)
    Wd[(size_t)(n0 + ty + r * 4) * 1024 + k0 + tx] = __float2bfloat16(T[tx][ty + r * 4]);
}

// ---------------- kernel 2: projection GEMM (r12-verified) ----------------
__global__ __launch_bounds__(256) void k_proj(
    const __hip_bfloat16* __restrict__ xb, const __hip_bfloat16* __restrict__ wt,
    const float* __restrict__ bq, const float* __restrict__ bk, const float* __restrict__ bv,
    __hip_bfloat16* __restrict__ Qb, __hip_bfloat16* __restrict__ Kb,
    __hip_bfloat16* __restrict__ Vt) {
  __shared__ char smem[32768];
  char* As = smem;            // [128 rows][64 bf16] = 128 B rows, 16 KB
  char* Bs = smem + 16384;
  const int orig = blockIdx.x;
  const int xcd = orig & 7, idx = orig >> 3;    // idx 0..95
  const int by = xcd * 4 + (idx & 3);           // 0..31
  const int bx = (idx >> 2) & 7;                // 0..7
  const int t = idx >> 5;                       // 0..2
  const char* X = (const char*)(xb + (size_t)t * 4194304);
  const char* W = (const char*)(wt + (size_t)t * 1048576);
  const float* bias = (t == 0) ? bq : (t == 1) ? bk : bv;
  const int m0 = by * 128, n0 = bx * 128;
  const int tid = threadIdx.x, w = tid >> 6, lane = tid & 63;
  const int l15 = lane & 15, g = lane >> 4;
  const int l8 = lane >> 3, l7 = lane & 7;
  const int vswz = ((l7 ^ l8) << 4);            // pre-swizzled 16B slot in 128B row
  const int wm = (w >> 1) * 64, wn = (w & 1) * 64;
  f32x4 acc[4][4];
#pragma unroll
  for (int i = 0; i < 4; ++i)
#pragma unroll
    for (int j = 0; j < 4; ++j) acc[i][j] = (f32x4){0.f, 0.f, 0.f, 0.f};

  for (int k0 = 0; k0 < 2048; k0 += 128) {      // 16 K-steps of 64 elems
    __syncthreads();
#pragma unroll
    for (int j = 0; j < 4; ++j) {
      const int ch = w * 4 + j;                 // 16 chunks of 8 rows
      gload16(X + (size_t)(m0 + ch * 8 + l8) * 2048 + k0 + vswz, As + ch * 1024);
      gload16(W + (size_t)(n0 + ch * 8 + l8) * 2048 + k0 + vswz, Bs + ch * 1024);
    }
    __syncthreads();
#pragma unroll
    for (int kk = 0; kk < 2; ++kk) {
      short8 af[4], bf_[4];
#pragma unroll
      for (int mt = 0; mt < 4; ++mt) {
        const int row = wm + mt * 16 + l15;
        af[mt] = *(const short8*)(As + row * 128 + ((kk * 64 + g * 16) ^ ((row & 7) << 4)));
      }
#pragma unroll
      for (int nt = 0; nt < 4; ++nt) {
        const int row = wn + nt * 16 + l15;
        bf_[nt] = *(const short8*)(Bs + row * 128 + ((kk * 64 + g * 16) ^ ((row & 7) << 4)));
      }
#pragma unroll
      for (int mt = 0; mt < 4; ++mt)
#pragma unroll
        for (int nt = 0; nt < 4; ++nt)
          acc[mt][nt] = __builtin_amdgcn_mfma_f32_16x16x32_bf16(af[mt], bf_[nt], acc[mt][nt], 0, 0, 0);
    }
  }

  float bv4[4];
#pragma unroll
  for (int nt = 0; nt < 4; ++nt) bv4[nt] = bias[n0 + wn + nt * 16 + l15];

  if (t < 2) {
    // Q/K epilogue: direct scatter (verified path)
#pragma unroll
    for (int mt = 0; mt < 4; ++mt) {
#pragma unroll
      for (int nt = 0; nt < 4; ++nt) {
        const int feat = n0 + wn + nt * 16 + l15;
        const int h = feat >> 6, d = feat & 63;
#pragma unroll
        for (int r = 0; r < 4; ++r) {
          const int token = m0 + wm + mt * 16 + g * 4 + r;
          const int b = token >> 11, s = token & 2047;
          const float val = acc[mt][nt][r] + bv4[nt];
          const __hip_bfloat16 hb = __float2bfloat16(val);
          if (t == 0) Qb[((size_t)(b * 16 + h) * 2048 + s) * 64 + d] = hb;
          else        Kb[((size_t)(b * 16 + h) * 2048 + s) * 64 + d] = hb;
        }
      }
    }
  } else {
    // V epilogue: LDS transpose -> coalesced stores, NATURAL key order (r7-verified)
    __hip_bfloat16* T2 = (__hip_bfloat16*)smem;
    const int bb = m0 >> 11;
    const int s0 = m0 & 2047;
#pragma unroll
    for (int p = 0; p < 2; ++p) {
      __syncthreads();
      if ((w >> 1) == p) {
#pragma unroll
        for (int mt = 0; mt < 4; ++mt)
#pragma unroll
          for (int nt = 0; nt < 4; ++nt) {
            const int feat = wn + nt * 16 + l15;
#pragma unroll
            for (int r = 0; r < 4; ++r) {
              const int tok = mt * 16 + g * 4 + r;
              T2[feat * 64 + (tok ^ ((feat & 7) << 3))] =
                  __float2bfloat16(acc[mt][nt][r] + bv4[nt]);
            }
          }
      }
      __syncthreads();
#pragma unroll
      for (int sw = 0; sw < 4; ++sw) {
        const int row = sw * 32 + (tid >> 3);
        const int c = tid & 7;
        const short8 vchunk = *(const short8*)(smem + row * 128 + 16 * (c ^ (row & 7)));
        const int gfeat = n0 + row;
        const int hh = gfeat >> 6, dd = gfeat & 63;
        *(short8*)(Vt + ((size_t)((bb * 16 + hh) * 64 + dd)) * 2048 + s0 + p * 64 + c * 8) = vchunk;
      }
    }
  }
}

// ---------------- kernel 3: flash attention (8 waves, 128 q/block) -------------
// 512 blocks (XCD-swizzled) x 512 threads. Staging halves per wave (1 K-chunk +
// 1 V-chunk); barrier-drain events halve; 16 waves/CU resident. All r12-verified
// data paths: permuted-K staging (all-K=32 MFMA), natural V, bias2 mask.
#define ATTN_BODY(CUR, NXT, PREF)                                              \
  {                                                                            \
    float4 mb[4];                                                              \
    _Pragma("unroll") for (int nt = 0; nt < 4; ++nt)                           \
        mb[nt] = *(const float4*)(mbp + (nt >> 1) * 32 + ((nt & 1) << 2) + g * 8); \
    mbp += 64;                                                                 \
    if (PREF) {                                                                \
      gload16(kst, Ks[NXT] + w * 1024);                                        \
      gload16(vst, Vs[NXT] + w * 1024);                                        \
    }                                                                          \
    kst += 8192; vst += 128;                                                   \
    f32x4 s_[4];                                                               \
    __builtin_amdgcn_s_setprio(1);                                             \
    _Pragma("unroll") for (int nt = 0; nt < 4; ++nt) {                         \
      s_[nt] = (f32x4){0.f, 0.f, 0.f, 0.f};                                    \
      const int key = nt * 16 + l15;                                           \
      _Pragma("unroll") for (int kc = 0; kc < 2; ++kc) {                       \
        const short8 kf = *(const short8*)(Ks[CUR] + key * 128 +               \
                           ((kc * 64 + g * 16) ^ ((key & 7) << 4)));           \
        s_[nt] = __builtin_amdgcn_mfma_f32_16x16x32_bf16(kf, aq[kc], s_[nt], 0, 0, 0); \
      }                                                                        \
    }                                                                          \
    __builtin_amdgcn_s_setprio(0);                                             \
    short8 pb8[2];                                                             \
    _Pragma("unroll") for (int c = 0; c < 2; ++c) {                            \
      union { short8 s8; __hip_bfloat16 hh[8]; } pu;                           \
      pu.hh[0] = __float2bfloat16(EXP2F(fmaf(s_[2*c][0], SC_L2E, mb[2*c].x))); \
      pu.hh[1] = __float2bfloat16(EXP2F(fmaf(s_[2*c][1], SC_L2E, mb[2*c].y))); \
      pu.hh[2] = __float2bfloat16(EXP2F(fmaf(s_[2*c][2], SC_L2E, mb[2*c].z))); \
      pu.hh[3] = __float2bfloat16(EXP2F(fmaf(s_[2*c][3], SC_L2E, mb[2*c].w))); \
      pu.hh[4] = __float2bfloat16(EXP2F(fmaf(s_[2*c+1][0], SC_L2E, mb[2*c+1].x))); \
      pu.hh[5] = __float2bfloat16(EXP2F(fmaf(s_[2*c+1][1], SC_L2E, mb[2*c+1].y))); \
      pu.hh[6] = __float2bfloat16(EXP2F(fmaf(s_[2*c+1][2], SC_L2E, mb[2*c+1].z))); \
      pu.hh[7] = __float2bfloat16(EXP2F(fmaf(s_[2*c+1][3], SC_L2E, mb[2*c+1].w))); \
      pb8[c] = pu.s8;                                                          \
    }                                                                          \
    __builtin_amdgcn_s_setprio(1);                                             \
    lacc = __builtin_amdgcn_mfma_f32_16x16x32_bf16(ones8, pb8[0], lacc, 0, 0, 0); \
    lacc = __builtin_amdgcn_mfma_f32_16x16x32_bf16(ones8, pb8[1], lacc, 0, 0, 0); \
    _Pragma("unroll") for (int dt = 0; dt < 4; ++dt) {                         \
      const int d = dt * 16 + l15;                                             \
      const int sw2 = (d & 7) << 4;                                            \
      f32x4 o = oaccT[dt];                                                     \
      const short8 v0 = *(const short8*)(Vs[CUR] + d * 128 + ((g * 16) ^ sw2)); \
      const short8 v1 = *(const short8*)(Vs[CUR] + d * 128 + ((64 + g * 16) ^ sw2)); \
      o = __builtin_amdgcn_mfma_f32_16x16x32_bf16(v0, pb8[0], o, 0, 0, 0);     \
      o = __builtin_amdgcn_mfma_f32_16x16x32_bf16(v1, pb8[1], o, 0, 0, 0);     \
      oaccT[dt] = o;                                                           \
    }                                                                          \
    __builtin_amdgcn_s_setprio(0);                                             \
    __syncthreads();                                                           \
  }

__global__ __launch_bounds__(512, 2) void k_attn(
    const __hip_bfloat16* __restrict__ Qb, const __hip_bfloat16* __restrict__ Kb,
    const __hip_bfloat16* __restrict__ Vt, const float* __restrict__ bias2,
    float* __restrict__ out) {
  __shared__ char Ks[2][8192];              // [64 key-slots][64 d] bf16, permuted keys
  __shared__ char Vs[2][8192];              // [64 d][64 keys] bf16, natural order
  const int orig = blockIdx.x;
  const int swz = (orig & 7) * 64 + (orig >> 3);   // bijective; 4 heads per XCD
  const int bh = swz >> 4, qb = swz & 15;
  const int b = bh >> 4, h = bh & 15;
  const int tid = threadIdx.x, w = tid >> 6, lane = tid & 63;
  const int g = lane >> 4, l15 = lane & 15;
  const char* Qc = (const char*)(Qb + (size_t)bh * 131072);
  const char* Kc = (const char*)(Kb + (size_t)bh * 131072);
  const char* Vc = (const char*)(Vt + (size_t)bh * 131072);

  const int l8 = lane >> 3, l7 = lane & 7;
  const int vswz = ((l7 ^ l8) << 4);        // pre-swizzled global 16B slot in 128B row

  // Q B-fragments: lane holds Q[q=l15][k = kc*32 + g*8 .. +7]
  short8 aq[2];
  const int arow = qb * 128 + w * 16 + l15;
#pragma unroll
  for (int kc = 0; kc < 2; ++kc)
    aq[kc] = *(const short8*)(Qc + (size_t)arow * 128 + kc * 64 + g * 16);

  f32x4 oaccT[4];                           // O^T: row d=dt*16+g*4+r, col q=l15
#pragma unroll
  for (int i = 0; i < 4; ++i) oaccT[i] = (f32x4){0.f, 0.f, 0.f, 0.f};
  f32x4 lacc = (f32x4){0.f, 0.f, 0.f, 0.f};   // denominator via ones-MFMA
  const short8 ones8 = {(short)0x3F80, (short)0x3F80, (short)0x3F80, (short)0x3F80,
                        (short)0x3F80, (short)0x3F80, (short)0x3F80, (short)0x3F80};

  // prologue: stage tile 0; wave w fills K chunk w (permuted) + V chunk w
  const int s = w * 8 + l8;                 // LDS slot-row this lane fills
  const int nt0 = s >> 4, gg = (s >> 2) & 3, rr = s & 3;
  const int kap = (nt0 >> 1) * 32 + gg * 8 + ((nt0 & 1) << 2) + rr;  // actual key
  const char* kst = Kc + (size_t)kap * 128 + vswz;
  const char* vst = Vc + (size_t)s * 4096 + vswz;
  gload16(kst, Ks[0] + w * 1024);
  gload16(vst, Vs[0] + w * 1024);
  kst += 8192;
  vst += 128;
  __syncthreads();

  const float* mbp = bias2 + b * 2048;
  for (int kt = 0; kt < 32; kt += 2) {
    ATTN_BODY(0, 1, true)
    ATTN_BODY(1, 0, (kt + 1 < 31))
  }

  // epilogue: lacc rows all equal the full denominator for this lane's q
  const float rl = 1.0f / lacc[0];
  float* orow = out + ((size_t)(b * 2048 + arow)) * 1024 + h * 64;
#pragma unroll
  for (int dt = 0; dt < 4; ++dt) {
    float4 st;
    st.x = oaccT[dt][0] * rl; st.y = oaccT[dt][1] * rl;
    st.z = oaccT[dt][2] * rl; st.w = oaccT[dt][3] * rl;
    *(float4*)(orow + dt * 16 + g * 4) = st;
  }
}

// ---------------- launcher ----------------
extern "C" void kernel_launch(void* const* d_in, const int* in_sizes, int n_in,
                              void* d_out, int out_size, void* d_ws, size_t ws_size,
                              hipStream_t stream) {
  const float* q   = (const float*)d_in[0];
  const float* k   = (const float*)d_in[1];
  const float* v   = (const float*)d_in[2];
  const int* mask  = (const int*)d_in[3];
  const float* Wq  = (const float*)d_in[4];
  const float* bq  = (const float*)d_in[5];
  const float* Wk  = (const float*)d_in[6];
  const float* bk  = (const float*)d_in[7];
  const float* Wv  = (const float*)d_in[8];
  const float* bv  = (const float*)d_in[9];
  float* out = (float*)d_out;
  char* ws = (char*)d_ws;
  __hip_bfloat16* Xb = (__hip_bfloat16*)(ws);
  __hip_bfloat16* Wt = (__hip_bfloat16*)(ws + 25165824);
  __hip_bfloat16* Qb = (__hip_bfloat16*)(ws + 31457280);
  __hip_bfloat16* Kb = (__hip_bfloat16*)(ws + 39845888);
  __hip_bfloat16* Vt = (__hip_bfloat16*)(ws + 48234496);
  float* bias2      = (float*)(ws + 56623104);   // 4096 floats

  k_cvt<<<dim3(6912), dim3(256), 0, stream>>>(q, k, v, Xb, Wq, Wk, Wv, Wt, mask, bias2);
  k_proj<<<dim3(768), dim3(256), 0, stream>>>(Xb, Wt, bq, bk, bv, Qb, Kb, Vt);
  k_attn<<<dim3(512), dim3(512), 0, stream>>>(Qb, Kb, Vt, bias2, out);
}

// Round 14
// 103.891 us; speedup vs baseline: 1.3179x; 1.0045x over previous
//
#include <hip/hip_runtime.h>
#include <hip/hip_bf16.h>

typedef __attribute__((ext_vector_type(8))) short short8;
typedef __attribute__((ext_vector_type(4))) float f32x4;

#define SC_L2E 0.4561727848849353f          // (1/sqrt(10)) * log2(e)

#if __has_builtin(__builtin_amdgcn_exp2f)
#define EXP2F __builtin_amdgcn_exp2f
#else
#define EXP2F exp2f
#endif

static __device__ __forceinline__ void gload16(const void* g, void* l) {
  __builtin_amdgcn_global_load_lds((const __attribute__((address_space(1))) void*)g,
                                   (__attribute__((address_space(3))) void*)l, 16, 0, 0);
}

// ---------------- kernel 1: fused converts (r9-verified) ----------------
__global__ void k_cvt(const float* __restrict__ q, const float* __restrict__ kk,
                      const float* __restrict__ v, __hip_bfloat16* __restrict__ xb,
                      const float* __restrict__ Wq, const float* __restrict__ Wk,
                      const float* __restrict__ Wv, __hip_bfloat16* __restrict__ wt,
                      const int* __restrict__ mask, float* __restrict__ bias2) {
  __shared__ float T[64][65];
  if (blockIdx.x < 6144) {
    const size_t i = ((size_t)blockIdx.x * 256 + threadIdx.x) * 8;
    const int t = (int)(i >> 22);               // 4194304 elements per tensor
    const float* src = (t == 0) ? q : (t == 1) ? kk : v;
    const size_t off = i & 4194303u;
    float4 f0 = *(const float4*)(src + off);
    float4 f1 = *(const float4*)(src + off + 4);
    union { short8 s; __hip_bfloat16 h[8]; } u;
    u.h[0] = __float2bfloat16(f0.x); u.h[1] = __float2bfloat16(f0.y);
    u.h[2] = __float2bfloat16(f0.z); u.h[3] = __float2bfloat16(f0.w);
    u.h[4] = __float2bfloat16(f1.x); u.h[5] = __float2bfloat16(f1.y);
    u.h[6] = __float2bfloat16(f1.z); u.h[7] = __float2bfloat16(f1.w);
    *(short8*)((char*)xb + i * 2) = u.s;
    return;
  }
  const int idx2 = blockIdx.x - 6144;           // 0..767
  const int z = idx2 >> 8;                      // 0..2
  const int r2 = idx2 & 255;
  const int bxi = r2 & 15, byi = r2 >> 4;
  if (z == 0 && byi == 0) {
    const int idx = bxi * 256 + threadIdx.x;
    bias2[idx] = mask[idx] ? -12.0f : -1e30f;   // static shift M=12 folded in
  }
  const float* W = (z == 0) ? Wq : (z == 1) ? Wk : Wv;
  __hip_bfloat16* Wd = wt + (size_t)z * 1048576;
  const int n0 = bxi * 64, k0 = byi * 64;
  const int tx = threadIdx.x & 63, ty = threadIdx.x >> 6;
#pragma unroll
  for (int r = 0; r < 16; ++r)
    T[ty + r * 4][tx] = W[(size_t)(k0 + ty + r * 4) * 1024 + n0 + tx];
  __syncthreads();
#pragma unroll
  for (int r = 0; r < 16; ++r)
    Wd[(size_t)(n0 + ty + r * 4) * 1024 + k0 + tx] = __float2bfloat16(T[tx][ty + r * 4]);
}

// ---------------- kernel 2: projection GEMM (r12-verified) ----------------
__global__ __launch_bounds__(256) void k_proj(
    const __hip_bfloat16* __restrict__ xb, const __hip_bfloat16* __restrict__ wt,
    const float* __restrict__ bq, const float* __restrict__ bk, const float* __restrict__ bv,
    __hip_bfloat16* __restrict__ Qb, __hip_bfloat16* __restrict__ Kb,
    __hip_bfloat16* __restrict__ Vt) {
  __shared__ char smem[32768];
  char* As = smem;            // [128 rows][64 bf16] = 128 B rows, 16 KB
  char* Bs = smem + 16384;
  const int orig = blockIdx.x;
  const int xcd = orig & 7, idx = orig >> 3;    // idx 0..95
  const int by = xcd * 4 + (idx & 3);           // 0..31
  const int bx = (idx >> 2) & 7;                // 0..7
  const int t = idx >> 5;                       // 0..2
  const char* X = (const char*)(xb + (size_t)t * 4194304);
  const char* W = (const char*)(wt + (size_t)t * 1048576);
  const float* bias = (t == 0) ? bq : (t == 1) ? bk : bv;
  const int m0 = by * 128, n0 = bx * 128;
  const int tid = threadIdx.x, w = tid >> 6, lane = tid & 63;
  const int l15 = lane & 15, g = lane >> 4;
  const int l8 = lane >> 3, l7 = lane & 7;
  const int vswz = ((l7 ^ l8) << 4);            // pre-swizzled 16B slot in 128B row
  const int wm = (w >> 1) * 64, wn = (w & 1) * 64;
  f32x4 acc[4][4];
#pragma unroll
  for (int i = 0; i < 4; ++i)
#pragma unroll
    for (int j = 0; j < 4; ++j) acc[i][j] = (f32x4){0.f, 0.f, 0.f, 0.f};

  for (int k0 = 0; k0 < 2048; k0 += 128) {      // 16 K-steps of 64 elems
    __syncthreads();
#pragma unroll
    for (int j = 0; j < 4; ++j) {
      const int ch = w * 4 + j;                 // 16 chunks of 8 rows
      gload16(X + (size_t)(m0 + ch * 8 + l8) * 2048 + k0 + vswz, As + ch * 1024);
      gload16(W + (size_t)(n0 + ch * 8 + l8) * 2048 + k0 + vswz, Bs + ch * 1024);
    }
    __syncthreads();
#pragma unroll
    for (int kk = 0; kk < 2; ++kk) {
      short8 af[4], bf_[4];
#pragma unroll
      for (int mt = 0; mt < 4; ++mt) {
        const int row = wm + mt * 16 + l15;
        af[mt] = *(const short8*)(As + row * 128 + ((kk * 64 + g * 16) ^ ((row & 7) << 4)));
      }
#pragma unroll
      for (int nt = 0; nt < 4; ++nt) {
        const int row = wn + nt * 16 + l15;
        bf_[nt] = *(const short8*)(Bs + row * 128 + ((kk * 64 + g * 16) ^ ((row & 7) << 4)));
      }
#pragma unroll
      for (int mt = 0; mt < 4; ++mt)
#pragma unroll
        for (int nt = 0; nt < 4; ++nt)
          acc[mt][nt] = __builtin_amdgcn_mfma_f32_16x16x32_bf16(af[mt], bf_[nt], acc[mt][nt], 0, 0, 0);
    }
  }

  float bv4[4];
#pragma unroll
  for (int nt = 0; nt < 4; ++nt) bv4[nt] = bias[n0 + wn + nt * 16 + l15];

  if (t < 2) {
    // Q/K epilogue: direct scatter (verified path)
#pragma unroll
    for (int mt = 0; mt < 4; ++mt) {
#pragma unroll
      for (int nt = 0; nt < 4; ++nt) {
        const int feat = n0 + wn + nt * 16 + l15;
        const int h = feat >> 6, d = feat & 63;
#pragma unroll
        for (int r = 0; r < 4; ++r) {
          const int token = m0 + wm + mt * 16 + g * 4 + r;
          const int b = token >> 11, s = token & 2047;
          const float val = acc[mt][nt][r] + bv4[nt];
          const __hip_bfloat16 hb = __float2bfloat16(val);
          if (t == 0) Qb[((size_t)(b * 16 + h) * 2048 + s) * 64 + d] = hb;
          else        Kb[((size_t)(b * 16 + h) * 2048 + s) * 64 + d] = hb;
        }
      }
    }
  } else {
    // V epilogue: LDS transpose -> coalesced stores, NATURAL key order (r7-verified)
    __hip_bfloat16* T2 = (__hip_bfloat16*)smem;
    const int bb = m0 >> 11;
    const int s0 = m0 & 2047;
#pragma unroll
    for (int p = 0; p < 2; ++p) {
      __syncthreads();
      if ((w >> 1) == p) {
#pragma unroll
        for (int mt = 0; mt < 4; ++mt)
#pragma unroll
          for (int nt = 0; nt < 4; ++nt) {
            const int feat = wn + nt * 16 + l15;
#pragma unroll
            for (int r = 0; r < 4; ++r) {
              const int tok = mt * 16 + g * 4 + r;
              T2[feat * 64 + (tok ^ ((feat & 7) << 3))] =
                  __float2bfloat16(acc[mt][nt][r] + bv4[nt]);
            }
          }
      }
      __syncthreads();
#pragma unroll
      for (int sw = 0; sw < 4; ++sw) {
        const int row = sw * 32 + (tid >> 3);
        const int c = tid & 7;
        const short8 vchunk = *(const short8*)(smem + row * 128 + 16 * (c ^ (row & 7)));
        const int gfeat = n0 + row;
        const int hh = gfeat >> 6, dd = gfeat & 63;
        *(short8*)(Vt + ((size_t)((bb * 16 + hh) * 64 + dd)) * 2048 + s0 + p * 64 + c * 8) = vchunk;
      }
    }
  }
}

// ---------------- kernel 3: flash attention (triple-buffer, counted vmcnt) -----
// 512 blocks (XCD-swizzled) x 512 threads (8 waves, 128 q). Depth-2 prefetch into
// 3 K/V buffers; end-of-body sync = s_waitcnt vmcnt(2) + s_barrier: the 2 loads
// just issued (tile t+2) stay in flight, tile t+1's loads (issued a full body ago)
// are proven complete. Mask loads issued before prefetch so their data-dependency
// wait leaves the prefetch outstanding. All r12/r13-verified data paths.
#define ATTN_BODY(CUR, PRF, PREF)                                              \
  {                                                                            \
    float4 mb[4];                                                              \
    _Pragma("unroll") for (int nt = 0; nt < 4; ++nt)                           \
        mb[nt] = *(const float4*)(mbp + (nt >> 1) * 32 + ((nt & 1) << 2) + g * 8); \
    mbp += 64;                                                                 \
    if (PREF) {                                                                \
      gload16(kst, Ks[PRF] + w * 1024);                                        \
      gload16(vst, Vs[PRF] + w * 1024);                                        \
    }                                                                          \
    kst += 8192; vst += 128;                                                   \
    f32x4 s_[4];                                                               \
    __builtin_amdgcn_s_setprio(1);                                             \
    _Pragma("unroll") for (int nt = 0; nt < 4; ++nt) {                         \
      s_[nt] = (f32x4){0.f, 0.f, 0.f, 0.f};                                    \
      const int key = nt * 16 + l15;                                           \
      _Pragma("unroll") for (int kc = 0; kc < 2; ++kc) {                       \
        const short8 kf = *(const short8*)(Ks[CUR] + key * 128 +               \
                           ((kc * 64 + g * 16) ^ ((key & 7) << 4)));           \
        s_[nt] = __builtin_amdgcn_mfma_f32_16x16x32_bf16(kf, aq[kc], s_[nt], 0, 0, 0); \
      }                                                                        \
    }                                                                          \
    __builtin_amdgcn_s_setprio(0);                                             \
    short8 pb8[2];                                                             \
    _Pragma("unroll") for (int c = 0; c < 2; ++c) {                            \
      union { short8 s8; __hip_bfloat16 hh[8]; } pu;                           \
      pu.hh[0] = __float2bfloat16(EXP2F(fmaf(s_[2*c][0], SC_L2E, mb[2*c].x))); \
      pu.hh[1] = __float2bfloat16(EXP2F(fmaf(s_[2*c][1], SC_L2E, mb[2*c].y))); \
      pu.hh[2] = __float2bfloat16(EXP2F(fmaf(s_[2*c][2], SC_L2E, mb[2*c].z))); \
      pu.hh[3] = __float2bfloat16(EXP2F(fmaf(s_[2*c][3], SC_L2E, mb[2*c].w))); \
      pu.hh[4] = __float2bfloat16(EXP2F(fmaf(s_[2*c+1][0], SC_L2E, mb[2*c+1].x))); \
      pu.hh[5] = __float2bfloat16(EXP2F(fmaf(s_[2*c+1][1], SC_L2E, mb[2*c+1].y))); \
      pu.hh[6] = __float2bfloat16(EXP2F(fmaf(s_[2*c+1][2], SC_L2E, mb[2*c+1].z))); \
      pu.hh[7] = __float2bfloat16(EXP2F(fmaf(s_[2*c+1][3], SC_L2E, mb[2*c+1].w))); \
      pb8[c] = pu.s8;                                                          \
    }                                                                          \
    __builtin_amdgcn_s_setprio(1);                                             \
    lacc = __builtin_amdgcn_mfma_f32_16x16x32_bf16(ones8, pb8[0], lacc, 0, 0, 0); \
    lacc = __builtin_amdgcn_mfma_f32_16x16x32_bf16(ones8, pb8[1], lacc, 0, 0, 0); \
    _Pragma("unroll") for (int dt = 0; dt < 4; ++dt) {                         \
      const int d = dt * 16 + l15;                                             \
      const int sw2 = (d & 7) << 4;                                            \
      f32x4 o = oaccT[dt];                                                     \
      const short8 v0 = *(const short8*)(Vs[CUR] + d * 128 + ((g * 16) ^ sw2)); \
      const short8 v1 = *(const short8*)(Vs[CUR] + d * 128 + ((64 + g * 16) ^ sw2)); \
      o = __builtin_amdgcn_mfma_f32_16x16x32_bf16(v0, pb8[0], o, 0, 0, 0);     \
      o = __builtin_amdgcn_mfma_f32_16x16x32_bf16(v1, pb8[1], o, 0, 0, 0);     \
      oaccT[dt] = o;                                                           \
    }                                                                          \
    __builtin_amdgcn_s_setprio(0);                                             \
    asm volatile("s_waitcnt vmcnt(2)" ::: "memory");                           \
    __builtin_amdgcn_s_barrier();                                              \
    __builtin_amdgcn_sched_barrier(0);                                         \
  }

__global__ __launch_bounds__(512, 2) void k_attn(
    const __hip_bfloat16* __restrict__ Qb, const __hip_bfloat16* __restrict__ Kb,
    const __hip_bfloat16* __restrict__ Vt, const float* __restrict__ bias2,
    float* __restrict__ out) {
  __shared__ char Ks[3][8192];              // [64 key-slots][64 d] bf16, permuted keys
  __shared__ char Vs[3][8192];              // [64 d][64 keys] bf16, natural order
  const int orig = blockIdx.x;
  const int swz = (orig & 7) * 64 + (orig >> 3);   // bijective; 4 heads per XCD
  const int bh = swz >> 4, qb = swz & 15;
  const int b = bh >> 4, h = bh & 15;
  const int tid = threadIdx.x, w = tid >> 6, lane = tid & 63;
  const int g = lane >> 4, l15 = lane & 15;
  const char* Qc = (const char*)(Qb + (size_t)bh * 131072);
  const char* Kc = (const char*)(Kb + (size_t)bh * 131072);
  const char* Vc = (const char*)(Vt + (size_t)bh * 131072);

  const int l8 = lane >> 3, l7 = lane & 7;
  const int vswz = ((l7 ^ l8) << 4);        // pre-swizzled global 16B slot in 128B row

  // Q B-fragments: lane holds Q[q=l15][k = kc*32 + g*8 .. +7]
  short8 aq[2];
  const int arow = qb * 128 + w * 16 + l15;
#pragma unroll
  for (int kc = 0; kc < 2; ++kc)
    aq[kc] = *(const short8*)(Qc + (size_t)arow * 128 + kc * 64 + g * 16);

  f32x4 oaccT[4];                           // O^T: row d=dt*16+g*4+r, col q=l15
#pragma unroll
  for (int i = 0; i < 4; ++i) oaccT[i] = (f32x4){0.f, 0.f, 0.f, 0.f};
  f32x4 lacc = (f32x4){0.f, 0.f, 0.f, 0.f};   // denominator via ones-MFMA
  const short8 ones8 = {(short)0x3F80, (short)0x3F80, (short)0x3F80, (short)0x3F80,
                        (short)0x3F80, (short)0x3F80, (short)0x3F80, (short)0x3F80};

  // prologue: stage tiles 0 and 1; wave w fills K chunk w (permuted) + V chunk w
  const int s = w * 8 + l8;                 // LDS slot-row this lane fills
  const int nt0 = s >> 4, gg = (s >> 2) & 3, rr = s & 3;
  const int kap = (nt0 >> 1) * 32 + gg * 8 + ((nt0 & 1) << 2) + rr;  // actual key
  const char* kst = Kc + (size_t)kap * 128 + vswz;
  const char* vst = Vc + (size_t)s * 4096 + vswz;
  gload16(kst, Ks[0] + w * 1024);
  gload16(vst, Vs[0] + w * 1024);
  kst += 8192; vst += 128;
  gload16(kst, Ks[1] + w * 1024);
  gload16(vst, Vs[1] + w * 1024);
  kst += 8192; vst += 128;
  asm volatile("s_waitcnt vmcnt(2)" ::: "memory");   // tile 0 landed; tile 1 in flight
  __builtin_amdgcn_s_barrier();
  __builtin_amdgcn_sched_barrier(0);

  const float* mbp = bias2 + b * 2048;
  for (int kt = 0; kt < 30; kt += 3) {
    ATTN_BODY(0, 2, true)
    ATTN_BODY(1, 0, true)
    ATTN_BODY(2, 1, true)
  }
  ATTN_BODY(0, 2, false)
  ATTN_BODY(1, 0, false)

  // epilogue: lacc rows all equal the full denominator for this lane's q
  const float rl = 1.0f / lacc[0];
  float* orow = out + ((size_t)(b * 2048 + arow)) * 1024 + h * 64;
#pragma unroll
  for (int dt = 0; dt < 4; ++dt) {
    float4 st;
    st.x = oaccT[dt][0] * rl; st.y = oaccT[dt][1] * rl;
    st.z = oaccT[dt][2] * rl; st.w = oaccT[dt][3] * rl;
    *(float4*)(orow + dt * 16 + g * 4) = st;
  }
}

// ---------------- launcher ----------------
extern "C" void kernel_launch(void* const* d_in, const int* in_sizes, int n_in,
                              void* d_out, int out_size, void* d_ws, size_t ws_size,
                              hipStream_t stream) {
  const float* q   = (const float*)d_in[0];
  const float* k   = (const float*)d_in[1];
  const float* v   = (const float*)d_in[2];
  const int* mask  = (const int*)d_in[3];
  const float* Wq  = (const float*)d_in[4];
  const float* bq  = (const float*)d_in[5];
  const float* Wk  = (const float*)d_in[6];
  const float* bk  = (const float*)d_in[7];
  const float* Wv  = (const float*)d_in[8];
  const float* bv  = (const float*)d_in[9];
  float* out = (float*)d_out;
  char* ws = (char*)d_ws;
  __hip_bfloat16* Xb = (__hip_bfloat16*)(ws);
  __hip_bfloat16* Wt = (__hip_bfloat16*)(ws + 25165824);
  __hip_bfloat16* Qb = (__hip_bfloat16*)(ws + 31457280);
  __hip_bfloat16* Kb = (__hip_bfloat16*)(ws + 39845888);
  __hip_bfloat16* Vt = (__hip_bfloat16*)(ws + 48234496);
  float* bias2      = (float*)(ws + 56623104);   // 4096 floats

  k_cvt<<<dim3(6912), dim3(256), 0, stream>>>(q, k, v, Xb, Wq, Wk, Wv, Wt, mask, bias2);
  k_proj<<<dim3(768), dim3(256), 0, stream>>>(Xb, Wt, bq, bk, bv, Qb, Kb, Vt);
  k_attn<<<dim3(512), dim3(512), 0, stream>>>(Qb, Kb, Vt, bias2, out);
}

// Round 15
// 103.822 us; speedup vs baseline: 1.3188x; 1.0007x over previous
//
#include <hip/hip_runtime.h>
#include <hip/hip_bf16.h>

typedef __attribute__((ext_vector_type(8))) short short8;
typedef __attribute__((ext_vector_type(4))) float f32x4;

#define SC_L2E 0.4561727848849353f          // (1/sqrt(10)) * log2(e)

#if __has_builtin(__builtin_amdgcn_exp2f)
#define EXP2F __builtin_amdgcn_exp2f
#else
#define EXP2F exp2f
#endif

static __device__ __forceinline__ void gload16(const void* g, void* l) {
  __builtin_amdgcn_global_load_lds((const __attribute__((address_space(1))) void*)g,
                                   (__attribute__((address_space(3))) void*)l, 16, 0, 0);
}

// ---------------- kernel 1: fused converts (r9-verified) ----------------
__global__ void k_cvt(const float* __restrict__ q, const float* __restrict__ kk,
                      const float* __restrict__ v, __hip_bfloat16* __restrict__ xb,
                      const float* __restrict__ Wq, const float* __restrict__ Wk,
                      const float* __restrict__ Wv, __hip_bfloat16* __restrict__ wt,
                      const int* __restrict__ mask, float* __restrict__ bias2) {
  __shared__ float T[64][65];
  if (blockIdx.x < 6144) {
    const size_t i = ((size_t)blockIdx.x * 256 + threadIdx.x) * 8;
    const int t = (int)(i >> 22);               // 4194304 elements per tensor
    const float* src = (t == 0) ? q : (t == 1) ? kk : v;
    const size_t off = i & 4194303u;
    float4 f0 = *(const float4*)(src + off);
    float4 f1 = *(const float4*)(src + off + 4);
    union { short8 s; __hip_bfloat16 h[8]; } u;
    u.h[0] = __float2bfloat16(f0.x); u.h[1] = __float2bfloat16(f0.y);
    u.h[2] = __float2bfloat16(f0.z); u.h[3] = __float2bfloat16(f0.w);
    u.h[4] = __float2bfloat16(f1.x); u.h[5] = __float2bfloat16(f1.y);
    u.h[6] = __float2bfloat16(f1.z); u.h[7] = __float2bfloat16(f1.w);
    *(short8*)((char*)xb + i * 2) = u.s;
    return;
  }
  const int idx2 = blockIdx.x - 6144;           // 0..767
  const int z = idx2 >> 8;                      // 0..2
  const int r2 = idx2 & 255;
  const int bxi = r2 & 15, byi = r2 >> 4;
  if (z == 0 && byi == 0) {
    const int idx = bxi * 256 + threadIdx.x;
    bias2[idx] = mask[idx] ? -12.0f : -1e30f;   // static shift M=12 folded in
  }
  const float* W = (z == 0) ? Wq : (z == 1) ? Wk : Wv;
  __hip_bfloat16* Wd = wt + (size_t)z * 1048576;
  const int n0 = bxi * 64, k0 = byi * 64;
  const int tx = threadIdx.x & 63, ty = threadIdx.x >> 6;
#pragma unroll
  for (int r = 0; r < 16; ++r)
    T[ty + r * 4][tx] = W[(size_t)(k0 + ty + r * 4) * 1024 + n0 + tx];
  __syncthreads();
#pragma unroll
  for (int r = 0; r < 16; ++r)
    Wd[(size_t)(n0 + ty + r * 4) * 1024 + k0 + tx] = __float2bfloat16(T[tx][ty + r * 4]);
}

// ---------------- kernel 2: projection GEMM (r12-verified) ----------------
__global__ __launch_bounds__(256) void k_proj(
    const __hip_bfloat16* __restrict__ xb, const __hip_bfloat16* __restrict__ wt,
    const float* __restrict__ bq, const float* __restrict__ bk, const float* __restrict__ bv,
    __hip_bfloat16* __restrict__ Qb, __hip_bfloat16* __restrict__ Kb,
    __hip_bfloat16* __restrict__ Vt) {
  __shared__ char smem[32768];
  char* As = smem;            // [128 rows][64 bf16] = 128 B rows, 16 KB
  char* Bs = smem + 16384;
  const int orig = blockIdx.x;
  const int xcd = orig & 7, idx = orig >> 3;    // idx 0..95
  const int by = xcd * 4 + (idx & 3);           // 0..31
  const int bx = (idx >> 2) & 7;                // 0..7
  const int t = idx >> 5;                       // 0..2
  const char* X = (const char*)(xb + (size_t)t * 4194304);
  const char* W = (const char*)(wt + (size_t)t * 1048576);
  const float* bias = (t == 0) ? bq : (t == 1) ? bk : bv;
  const int m0 = by * 128, n0 = bx * 128;
  const int tid = threadIdx.x, w = tid >> 6, lane = tid & 63;
  const int l15 = lane & 15, g = lane >> 4;
  const int l8 = lane >> 3, l7 = lane & 7;
  const int vswz = ((l7 ^ l8) << 4);            // pre-swizzled 16B slot in 128B row
  const int wm = (w >> 1) * 64, wn = (w & 1) * 64;
  f32x4 acc[4][4];
#pragma unroll
  for (int i = 0; i < 4; ++i)
#pragma unroll
    for (int j = 0; j < 4; ++j) acc[i][j] = (f32x4){0.f, 0.f, 0.f, 0.f};

  for (int k0 = 0; k0 < 2048; k0 += 128) {      // 16 K-steps of 64 elems
    __syncthreads();
#pragma unroll
    for (int j = 0; j < 4; ++j) {
      const int ch = w * 4 + j;                 // 16 chunks of 8 rows
      gload16(X + (size_t)(m0 + ch * 8 + l8) * 2048 + k0 + vswz, As + ch * 1024);
      gload16(W + (size_t)(n0 + ch * 8 + l8) * 2048 + k0 + vswz, Bs + ch * 1024);
    }
    __syncthreads();
#pragma unroll
    for (int kk = 0; kk < 2; ++kk) {
      short8 af[4], bf_[4];
#pragma unroll
      for (int mt = 0; mt < 4; ++mt) {
        const int row = wm + mt * 16 + l15;
        af[mt] = *(const short8*)(As + row * 128 + ((kk * 64 + g * 16) ^ ((row & 7) << 4)));
      }
#pragma unroll
      for (int nt = 0; nt < 4; ++nt) {
        const int row = wn + nt * 16 + l15;
        bf_[nt] = *(const short8*)(Bs + row * 128 + ((kk * 64 + g * 16) ^ ((row & 7) << 4)));
      }
#pragma unroll
      for (int mt = 0; mt < 4; ++mt)
#pragma unroll
        for (int nt = 0; nt < 4; ++nt)
          acc[mt][nt] = __builtin_amdgcn_mfma_f32_16x16x32_bf16(af[mt], bf_[nt], acc[mt][nt], 0, 0, 0);
    }
  }

  float bv4[4];
#pragma unroll
  for (int nt = 0; nt < 4; ++nt) bv4[nt] = bias[n0 + wn + nt * 16 + l15];

  if (t < 2) {
    // Q/K epilogue: direct scatter (verified path)
#pragma unroll
    for (int mt = 0; mt < 4; ++mt) {
#pragma unroll
      for (int nt = 0; nt < 4; ++nt) {
        const int feat = n0 + wn + nt * 16 + l15;
        const int h = feat >> 6, d = feat & 63;
#pragma unroll
        for (int r = 0; r < 4; ++r) {
          const int token = m0 + wm + mt * 16 + g * 4 + r;
          const int b = token >> 11, s = token & 2047;
          const float val = acc[mt][nt][r] + bv4[nt];
          const __hip_bfloat16 hb = __float2bfloat16(val);
          if (t == 0) Qb[((size_t)(b * 16 + h) * 2048 + s) * 64 + d] = hb;
          else        Kb[((size_t)(b * 16 + h) * 2048 + s) * 64 + d] = hb;
        }
      }
    }
  } else {
    // V epilogue: LDS transpose -> coalesced stores, NATURAL key order (r7-verified)
    __hip_bfloat16* T2 = (__hip_bfloat16*)smem;
    const int bb = m0 >> 11;
    const int s0 = m0 & 2047;
#pragma unroll
    for (int p = 0; p < 2; ++p) {
      __syncthreads();
      if ((w >> 1) == p) {
#pragma unroll
        for (int mt = 0; mt < 4; ++mt)
#pragma unroll
          for (int nt = 0; nt < 4; ++nt) {
            const int feat = wn + nt * 16 + l15;
#pragma unroll
            for (int r = 0; r < 4; ++r) {
              const int tok = mt * 16 + g * 4 + r;
              T2[feat * 64 + (tok ^ ((feat & 7) << 3))] =
                  __float2bfloat16(acc[mt][nt][r] + bv4[nt]);
            }
          }
      }
      __syncthreads();
#pragma unroll
      for (int sw = 0; sw < 4; ++sw) {
        const int row = sw * 32 + (tid >> 3);
        const int c = tid & 7;
        const short8 vchunk = *(const short8*)(smem + row * 128 + 16 * (c ^ (row & 7)));
        const int gfeat = n0 + row;
        const int hh = gfeat >> 6, dd = gfeat & 63;
        *(short8*)(Vt + ((size_t)((bb * 16 + hh) * 64 + dd)) * 2048 + s0 + p * 64 + c * 8) = vchunk;
      }
    }
  }
}

// ---------------- kernel 3: flash attention (QK one tile ahead, 4 buffers) -----
// 512 blocks (XCD-swizzled) x 512 threads. Body t: QK(t+1) -> SN (results used
// next body: MFMA latency hidden behind barrier), softmax(tile t, SP: computed
// last body, already resolved -> no wait), PV(t). Depth-3 prefetch, 4 buffers;
// vmcnt(2) leaves only tile t+3's pair in flight. All r12-14-verified data paths.
#define ATTN_BODY(CUR, NXT, PRF, SP, SN, DOQK, DOPREF, SYNC)                   \
  {                                                                            \
    float4 mb[4];                                                              \
    _Pragma("unroll") for (int nt = 0; nt < 4; ++nt)                           \
        mb[nt] = *(const float4*)(mbp + (nt >> 1) * 32 + ((nt & 1) << 2) + g * 8); \
    mbp += 64;                                                                 \
    __builtin_amdgcn_sched_barrier(0);  /* mb loads issue before gloads */     \
    if (DOPREF) {                                                              \
      gload16(kst, Ks[PRF] + w * 1024);                                        \
      gload16(vst, Vs[PRF] + w * 1024);                                        \
    }                                                                          \
    kst += 8192; vst += 128;                                                   \
    if (DOQK) {                                                                \
      __builtin_amdgcn_s_setprio(1);                                           \
      _Pragma("unroll") for (int nt = 0; nt < 4; ++nt) {                       \
        SN[nt] = (f32x4){0.f, 0.f, 0.f, 0.f};                                  \
        const int key = nt * 16 + l15;                                         \
        _Pragma("unroll") for (int kc = 0; kc < 2; ++kc) {                     \
          const short8 kf = *(const short8*)(Ks[NXT] + key * 128 +             \
                             ((kc * 64 + g * 16) ^ ((key & 7) << 4)));         \
          SN[nt] = __builtin_amdgcn_mfma_f32_16x16x32_bf16(kf, aq[kc], SN[nt], 0, 0, 0); \
        }                                                                      \
      }                                                                        \
      __builtin_amdgcn_s_setprio(0);                                           \
    }                                                                          \
    short8 pb8[2];                                                             \
    _Pragma("unroll") for (int c = 0; c < 2; ++c) {                            \
      union { short8 s8; __hip_bfloat16 hh[8]; } pu;                           \
      pu.hh[0] = __float2bfloat16(EXP2F(fmaf(SP[2*c][0], SC_L2E, mb[2*c].x))); \
      pu.hh[1] = __float2bfloat16(EXP2F(fmaf(SP[2*c][1], SC_L2E, mb[2*c].y))); \
      pu.hh[2] = __float2bfloat16(EXP2F(fmaf(SP[2*c][2], SC_L2E, mb[2*c].z))); \
      pu.hh[3] = __float2bfloat16(EXP2F(fmaf(SP[2*c][3], SC_L2E, mb[2*c].w))); \
      pu.hh[4] = __float2bfloat16(EXP2F(fmaf(SP[2*c+1][0], SC_L2E, mb[2*c+1].x))); \
      pu.hh[5] = __float2bfloat16(EXP2F(fmaf(SP[2*c+1][1], SC_L2E, mb[2*c+1].y))); \
      pu.hh[6] = __float2bfloat16(EXP2F(fmaf(SP[2*c+1][2], SC_L2E, mb[2*c+1].z))); \
      pu.hh[7] = __float2bfloat16(EXP2F(fmaf(SP[2*c+1][3], SC_L2E, mb[2*c+1].w))); \
      pb8[c] = pu.s8;                                                          \
    }                                                                          \
    __builtin_amdgcn_s_setprio(1);                                             \
    lacc = __builtin_amdgcn_mfma_f32_16x16x32_bf16(ones8, pb8[0], lacc, 0, 0, 0); \
    lacc = __builtin_amdgcn_mfma_f32_16x16x32_bf16(ones8, pb8[1], lacc, 0, 0, 0); \
    _Pragma("unroll") for (int dt = 0; dt < 4; ++dt) {                         \
      const int d = dt * 16 + l15;                                             \
      const int sw2 = (d & 7) << 4;                                            \
      f32x4 o = oaccT[dt];                                                     \
      const short8 v0 = *(const short8*)(Vs[CUR] + d * 128 + ((g * 16) ^ sw2)); \
      const short8 v1 = *(const short8*)(Vs[CUR] + d * 128 + ((64 + g * 16) ^ sw2)); \
      o = __builtin_amdgcn_mfma_f32_16x16x32_bf16(v0, pb8[0], o, 0, 0, 0);     \
      o = __builtin_amdgcn_mfma_f32_16x16x32_bf16(v1, pb8[1], o, 0, 0, 0);     \
      oaccT[dt] = o;                                                           \
    }                                                                          \
    __builtin_amdgcn_s_setprio(0);                                             \
    if (SYNC == 2) { asm volatile("s_waitcnt vmcnt(2)" ::: "memory"); }        \
    else if (SYNC == 0) { asm volatile("s_waitcnt vmcnt(0)" ::: "memory"); }   \
    if (SYNC >= 0) {                                                           \
      __builtin_amdgcn_s_barrier();                                            \
      __builtin_amdgcn_sched_barrier(0);                                       \
    }                                                                          \
  }

__global__ __launch_bounds__(512, 2) void k_attn(
    const __hip_bfloat16* __restrict__ Qb, const __hip_bfloat16* __restrict__ Kb,
    const __hip_bfloat16* __restrict__ Vt, const float* __restrict__ bias2,
    float* __restrict__ out) {
  __shared__ char Ks[4][8192];              // [64 key-slots][64 d] bf16, permuted keys
  __shared__ char Vs[4][8192];              // [64 d][64 keys] bf16, natural order
  const int orig = blockIdx.x;
  const int swz = (orig & 7) * 64 + (orig >> 3);   // bijective; 4 heads per XCD
  const int bh = swz >> 4, qb = swz & 15;
  const int b = bh >> 4, h = bh & 15;
  const int tid = threadIdx.x, w = tid >> 6, lane = tid & 63;
  const int g = lane >> 4, l15 = lane & 15;
  const char* Qc = (const char*)(Qb + (size_t)bh * 131072);
  const char* Kc = (const char*)(Kb + (size_t)bh * 131072);
  const char* Vc = (const char*)(Vt + (size_t)bh * 131072);

  const int l8 = lane >> 3, l7 = lane & 7;
  const int vswz = ((l7 ^ l8) << 4);        // pre-swizzled global 16B slot in 128B row

  // Q B-fragments: lane holds Q[q=l15][k = kc*32 + g*8 .. +7]
  short8 aq[2];
  const int arow = qb * 128 + w * 16 + l15;
#pragma unroll
  for (int kc = 0; kc < 2; ++kc)
    aq[kc] = *(const short8*)(Qc + (size_t)arow * 128 + kc * 64 + g * 16);

  f32x4 oaccT[4];                           // O^T: row d=dt*16+g*4+r, col q=l15
#pragma unroll
  for (int i = 0; i < 4; ++i) oaccT[i] = (f32x4){0.f, 0.f, 0.f, 0.f};
  f32x4 lacc = (f32x4){0.f, 0.f, 0.f, 0.f};   // denominator via ones-MFMA
  const short8 ones8 = {(short)0x3F80, (short)0x3F80, (short)0x3F80, (short)0x3F80,
                        (short)0x3F80, (short)0x3F80, (short)0x3F80, (short)0x3F80};
  f32x4 sA[4], sB[4];                       // score ping-pong (literal names)

  // prologue: stage tiles 0,1,2; wave w fills K chunk w (permuted) + V chunk w
  const int slot = w * 8 + l8;              // LDS slot-row this lane fills
  const int nt0 = slot >> 4, gg = (slot >> 2) & 3, rr = slot & 3;
  const int kap = (nt0 >> 1) * 32 + gg * 8 + ((nt0 & 1) << 2) + rr;  // actual key
  const char* kst = Kc + (size_t)kap * 128 + vswz;
  const char* vst = Vc + (size_t)slot * 4096 + vswz;
#pragma unroll
  for (int tpre = 0; tpre < 3; ++tpre) {
    gload16(kst, Ks[tpre] + w * 1024);
    gload16(vst, Vs[tpre] + w * 1024);
    kst += 8192; vst += 128;
  }
  asm volatile("s_waitcnt vmcnt(2)" ::: "memory");   // tiles 0,1 landed; tile 2 in flight
  __builtin_amdgcn_s_barrier();
  __builtin_amdgcn_sched_barrier(0);

  // QK(tile 0) -> sA
  __builtin_amdgcn_s_setprio(1);
#pragma unroll
  for (int nt = 0; nt < 4; ++nt) {
    sA[nt] = (f32x4){0.f, 0.f, 0.f, 0.f};
    const int key = nt * 16 + l15;
#pragma unroll
    for (int kc = 0; kc < 2; ++kc) {
      const short8 kf = *(const short8*)(Ks[0] + key * 128 +
                         ((kc * 64 + g * 16) ^ ((key & 7) << 4)));
      sA[nt] = __builtin_amdgcn_mfma_f32_16x16x32_bf16(kf, aq[kc], sA[nt], 0, 0, 0);
    }
  }
  __builtin_amdgcn_s_setprio(0);

  const float* mbp = bias2 + b * 2048;
  for (int k = 0; k < 7; ++k) {             // t = 0..27
    ATTN_BODY(0, 1, 3, sA, sB, 1, 1, 2)
    ATTN_BODY(1, 2, 0, sB, sA, 1, 1, 2)
    ATTN_BODY(2, 3, 1, sA, sB, 1, 1, 2)
    ATTN_BODY(3, 0, 2, sB, sA, 1, 1, 2)
  }
  ATTN_BODY(0, 1, 3, sA, sB, 1, 1, 2)       // t=28: prefetch tile 31
  ATTN_BODY(1, 2, 0, sB, sA, 1, 0, 0)       // t=29: drain (tile 31 lands)
  ATTN_BODY(2, 3, 1, sA, sB, 1, 0, 0)       // t=30: QK(31)
  ATTN_BODY(3, 0, 2, sB, sA, 0, 0, -1)      // t=31: softmax+PV only

  // epilogue: lacc rows all equal the full denominator for this lane's q
  const float rl = 1.0f / lacc[0];
  float* orow = out + ((size_t)(b * 2048 + arow)) * 1024 + h * 64;
#pragma unroll
  for (int dt = 0; dt < 4; ++dt) {
    float4 st;
    st.x = oaccT[dt][0] * rl; st.y = oaccT[dt][1] * rl;
    st.z = oaccT[dt][2] * rl; st.w = oaccT[dt][3] * rl;
    *(float4*)(orow + dt * 16 + g * 4) = st;
  }
}

// ---------------- launcher ----------------
extern "C" void kernel_launch(void* const* d_in, const int* in_sizes, int n_in,
                              void* d_out, int out_size, void* d_ws, size_t ws_size,
                              hipStream_t stream) {
  const float* q   = (const float*)d_in[0];
  const float* k   = (const float*)d_in[1];
  const float* v   = (const float*)d_in[2];
  const int* mask  = (const int*)d_in[3];
  const float* Wq  = (const float*)d_in[4];
  const float* bq  = (const float*)d_in[5];
  const float* Wk  = (const float*)d_in[6];
  const float* bk  = (const float*)d_in[7];
  const float* Wv  = (const float*)d_in[8];
  const float* bv  = (const float*)d_in[9];
  float* out = (float*)d_out;
  char* ws = (char*)d_ws;
  __hip_bfloat16* Xb = (__hip_bfloat16*)(ws);
  __hip_bfloat16* Wt = (__hip_bfloat16*)(ws + 25165824);
  __hip_bfloat16* Qb = (__hip_bfloat16*)(ws + 31457280);
  __hip_bfloat16* Kb = (__hip_bfloat16*)(ws + 39845888);
  __hip_bfloat16* Vt = (__hip_bfloat16*)(ws + 48234496);
  float* bias2      = (float*)(ws + 56623104);   // 4096 floats

  k_cvt<<<dim3(6912), dim3(256), 0, stream>>>(q, k, v, Xb, Wq, Wk, Wv, Wt, mask, bias2);
  k_proj<<<dim3(768), dim3(256), 0, stream>>>(Xb, Wt, bq, bk, bv, Qb, Kb, Vt);
  k_attn<<<dim3(512), dim3(512), 0, stream>>>(Qb, Kb, Vt, bias2, out);
}

// Round 16
// 102.435 us; speedup vs baseline: 1.3367x; 1.0135x over previous
//
#include <hip/hip_runtime.h>
#include <hip/hip_bf16.h>

typedef __attribute__((ext_vector_type(8))) short short8;
typedef __attribute__((ext_vector_type(4))) float f32x4;

#define SC_L2E 0.4561727848849353f          // (1/sqrt(10)) * log2(e)

#if __has_builtin(__builtin_amdgcn_exp2f)
#define EXP2F __builtin_amdgcn_exp2f
#else
#define EXP2F exp2f
#endif

static __device__ __forceinline__ void gload16(const void* g, void* l) {
  __builtin_amdgcn_global_load_lds((const __attribute__((address_space(1))) void*)g,
                                   (__attribute__((address_space(3))) void*)l, 16, 0, 0);
}

// ---------------- kernel 1: fused converts (r9-verified) ----------------
__global__ void k_cvt(const float* __restrict__ q, const float* __restrict__ kk,
                      const float* __restrict__ v, __hip_bfloat16* __restrict__ xb,
                      const float* __restrict__ Wq, const float* __restrict__ Wk,
                      const float* __restrict__ Wv, __hip_bfloat16* __restrict__ wt,
                      const int* __restrict__ mask, float* __restrict__ bias2) {
  __shared__ float T[64][65];
  if (blockIdx.x < 6144) {
    const size_t i = ((size_t)blockIdx.x * 256 + threadIdx.x) * 8;
    const int t = (int)(i >> 22);               // 4194304 elements per tensor
    const float* src = (t == 0) ? q : (t == 1) ? kk : v;
    const size_t off = i & 4194303u;
    float4 f0 = *(const float4*)(src + off);
    float4 f1 = *(const float4*)(src + off + 4);
    union { short8 s; __hip_bfloat16 h[8]; } u;
    u.h[0] = __float2bfloat16(f0.x); u.h[1] = __float2bfloat16(f0.y);
    u.h[2] = __float2bfloat16(f0.z); u.h[3] = __float2bfloat16(f0.w);
    u.h[4] = __float2bfloat16(f1.x); u.h[5] = __float2bfloat16(f1.y);
    u.h[6] = __float2bfloat16(f1.z); u.h[7] = __float2bfloat16(f1.w);
    *(short8*)((char*)xb + i * 2) = u.s;
    return;
  }
  const int idx2 = blockIdx.x - 6144;           // 0..767
  const int z = idx2 >> 8;                      // 0..2
  const int r2 = idx2 & 255;
  const int bxi = r2 & 15, byi = r2 >> 4;
  if (z == 0 && byi == 0) {
    const int idx = bxi * 256 + threadIdx.x;
    bias2[idx] = mask[idx] ? -12.0f : -1e30f;   // static shift M=12 folded in
  }
  const float* W = (z == 0) ? Wq : (z == 1) ? Wk : Wv;
  __hip_bfloat16* Wd = wt + (size_t)z * 1048576;
  const int n0 = bxi * 64, k0 = byi * 64;
  const int tx = threadIdx.x & 63, ty = threadIdx.x >> 6;
#pragma unroll
  for (int r = 0; r < 16; ++r)
    T[ty + r * 4][tx] = W[(size_t)(k0 + ty + r * 4) * 1024 + n0 + tx];
  __syncthreads();
#pragma unroll
  for (int r = 0; r < 16; ++r)
    Wd[(size_t)(n0 + ty + r * 4) * 1024 + k0 + tx] = __float2bfloat16(T[tx][ty + r * 4]);
}

// ---------------- kernel 2: projection GEMM (r12-verified) ----------------
__global__ __launch_bounds__(256) void k_proj(
    const __hip_bfloat16* __restrict__ xb, const __hip_bfloat16* __restrict__ wt,
    const float* __restrict__ bq, const float* __restrict__ bk, const float* __restrict__ bv,
    __hip_bfloat16* __restrict__ Qb, __hip_bfloat16* __restrict__ Kb,
    __hip_bfloat16* __restrict__ Vt) {
  __shared__ char smem[32768];
  char* As = smem;            // [128 rows][64 bf16] = 128 B rows, 16 KB
  char* Bs = smem + 16384;
  const int orig = blockIdx.x;
  const int xcd = orig & 7, idx = orig >> 3;    // idx 0..95
  const int by = xcd * 4 + (idx & 3);           // 0..31
  const int bx = (idx >> 2) & 7;                // 0..7
  const int t = idx >> 5;                       // 0..2
  const char* X = (const char*)(xb + (size_t)t * 4194304);
  const char* W = (const char*)(wt + (size_t)t * 1048576);
  const float* bias = (t == 0) ? bq : (t == 1) ? bk : bv;
  const int m0 = by * 128, n0 = bx * 128;
  const int tid = threadIdx.x, w = tid >> 6, lane = tid & 63;
  const int l15 = lane & 15, g = lane >> 4;
  const int l8 = lane >> 3, l7 = lane & 7;
  const int vswz = ((l7 ^ l8) << 4);            // pre-swizzled 16B slot in 128B row
  const int wm = (w >> 1) * 64, wn = (w & 1) * 64;
  f32x4 acc[4][4];
#pragma unroll
  for (int i = 0; i < 4; ++i)
#pragma unroll
    for (int j = 0; j < 4; ++j) acc[i][j] = (f32x4){0.f, 0.f, 0.f, 0.f};

  for (int k0 = 0; k0 < 2048; k0 += 128) {      // 16 K-steps of 64 elems
    __syncthreads();
#pragma unroll
    for (int j = 0; j < 4; ++j) {
      const int ch = w * 4 + j;                 // 16 chunks of 8 rows
      gload16(X + (size_t)(m0 + ch * 8 + l8) * 2048 + k0 + vswz, As + ch * 1024);
      gload16(W + (size_t)(n0 + ch * 8 + l8) * 2048 + k0 + vswz, Bs + ch * 1024);
    }
    __syncthreads();
#pragma unroll
    for (int kk = 0; kk < 2; ++kk) {
      short8 af[4], bf_[4];
#pragma unroll
      for (int mt = 0; mt < 4; ++mt) {
        const int row = wm + mt * 16 + l15;
        af[mt] = *(const short8*)(As + row * 128 + ((kk * 64 + g * 16) ^ ((row & 7) << 4)));
      }
#pragma unroll
      for (int nt = 0; nt < 4; ++nt) {
        const int row = wn + nt * 16 + l15;
        bf_[nt] = *(const short8*)(Bs + row * 128 + ((kk * 64 + g * 16) ^ ((row & 7) << 4)));
      }
#pragma unroll
      for (int mt = 0; mt < 4; ++mt)
#pragma unroll
        for (int nt = 0; nt < 4; ++nt)
          acc[mt][nt] = __builtin_amdgcn_mfma_f32_16x16x32_bf16(af[mt], bf_[nt], acc[mt][nt], 0, 0, 0);
    }
  }

  float bv4[4];
#pragma unroll
  for (int nt = 0; nt < 4; ++nt) bv4[nt] = bias[n0 + wn + nt * 16 + l15];

  if (t < 2) {
    // Q/K epilogue: direct scatter (verified path)
#pragma unroll
    for (int mt = 0; mt < 4; ++mt) {
#pragma unroll
      for (int nt = 0; nt < 4; ++nt) {
        const int feat = n0 + wn + nt * 16 + l15;
        const int h = feat >> 6, d = feat & 63;
#pragma unroll
        for (int r = 0; r < 4; ++r) {
          const int token = m0 + wm + mt * 16 + g * 4 + r;
          const int b = token >> 11, s = token & 2047;
          const float val = acc[mt][nt][r] + bv4[nt];
          const __hip_bfloat16 hb = __float2bfloat16(val);
          if (t == 0) Qb[((size_t)(b * 16 + h) * 2048 + s) * 64 + d] = hb;
          else        Kb[((size_t)(b * 16 + h) * 2048 + s) * 64 + d] = hb;
        }
      }
    }
  } else {
    // V epilogue: LDS transpose -> coalesced stores, NATURAL key order (r7-verified)
    __hip_bfloat16* T2 = (__hip_bfloat16*)smem;
    const int bb = m0 >> 11;
    const int s0 = m0 & 2047;
#pragma unroll
    for (int p = 0; p < 2; ++p) {
      __syncthreads();
      if ((w >> 1) == p) {
#pragma unroll
        for (int mt = 0; mt < 4; ++mt)
#pragma unroll
          for (int nt = 0; nt < 4; ++nt) {
            const int feat = wn + nt * 16 + l15;
#pragma unroll
            for (int r = 0; r < 4; ++r) {
              const int tok = mt * 16 + g * 4 + r;
              T2[feat * 64 + (tok ^ ((feat & 7) << 3))] =
                  __float2bfloat16(acc[mt][nt][r] + bv4[nt]);
            }
          }
      }
      __syncthreads();
#pragma unroll
      for (int sw = 0; sw < 4; ++sw) {
        const int row = sw * 32 + (tid >> 3);
        const int c = tid & 7;
        const short8 vchunk = *(const short8*)(smem + row * 128 + 16 * (c ^ (row & 7)));
        const int gfeat = n0 + row;
        const int hh = gfeat >> 6, dd = gfeat & 63;
        *(short8*)(Vt + ((size_t)((bb * 16 + hh) * 64 + dd)) * 2048 + s0 + p * 64 + c * 8) = vchunk;
      }
    }
  }
}

// ---------------- kernel 3: flash attention (2 q-tiles/wave, shared frag reads) -
// 512 blocks (XCD-swizzled) x 256 threads (4 waves x 32 q = 128 q/block).
// K/V fragment b128 reads are issued ONCE per body and feed BOTH q-tiles' MFMAs
// -> LDS read traffic halves vs r15. Triple-buffer, counted vmcnt(4) (4 gloads/
// wave/tile). All r12-15-verified data paths: permuted-K staging (all-K=32 MFMA),
// natural V, bias2 static-max mask.
#define ATTN_BODY(CUR, PRF, DOPREF, SYNC)                                      \
  {                                                                            \
    float4 mb[4];                                                              \
    _Pragma("unroll") for (int nt = 0; nt < 4; ++nt)                           \
        mb[nt] = *(const float4*)(mbp + (nt >> 1) * 32 + ((nt & 1) << 2) + g * 8); \
    mbp += 64;                                                                 \
    __builtin_amdgcn_sched_barrier(0);  /* mb loads issue before gloads */     \
    if (DOPREF) {                                                              \
      _Pragma("unroll") for (int j = 0; j < 2; ++j) {                          \
        gload16(kst[j], Ks[PRF] + (w * 2 + j) * 1024);                         \
        gload16(vst[j], Vs[PRF] + (w * 2 + j) * 1024);                         \
      }                                                                        \
    }                                                                          \
    kst[0] += 8192; kst[1] += 8192; vst[0] += 128; vst[1] += 128;              \
    f32x4 sA[4], sB[4];                                                        \
    __builtin_amdgcn_s_setprio(1);                                             \
    _Pragma("unroll") for (int nt = 0; nt < 4; ++nt) {                         \
      const int key = nt * 16 + l15;                                           \
      const int ksw = (key & 7) << 4;                                          \
      const short8 kf0 = *(const short8*)(Ks[CUR] + key * 128 + ((g * 16) ^ ksw)); \
      const short8 kf1 = *(const short8*)(Ks[CUR] + key * 128 + ((64 + g * 16) ^ ksw)); \
      f32x4 z = (f32x4){0.f, 0.f, 0.f, 0.f};                                   \
      sA[nt] = __builtin_amdgcn_mfma_f32_16x16x32_bf16(kf0, aq[0][0], z, 0, 0, 0); \
      sA[nt] = __builtin_amdgcn_mfma_f32_16x16x32_bf16(kf1, aq[0][1], sA[nt], 0, 0, 0); \
      sB[nt] = __builtin_amdgcn_mfma_f32_16x16x32_bf16(kf0, aq[1][0], z, 0, 0, 0); \
      sB[nt] = __builtin_amdgcn_mfma_f32_16x16x32_bf16(kf1, aq[1][1], sB[nt], 0, 0, 0); \
    }                                                                          \
    __builtin_amdgcn_s_setprio(0);                                             \
    short8 pbA[2], pbB[2];                                                     \
    _Pragma("unroll") for (int c = 0; c < 2; ++c) {                            \
      union { short8 s8; __hip_bfloat16 hh[8]; } pa, pb;                       \
      _Pragma("unroll") for (int e = 0; e < 8; ++e) {                          \
        const int nt = 2 * c + (e >> 2);                                       \
        const float mbe = (e & 3) == 0 ? mb[nt].x : (e & 3) == 1 ? mb[nt].y :  \
                          (e & 3) == 2 ? mb[nt].z : mb[nt].w;                  \
        pa.hh[e] = __float2bfloat16(EXP2F(fmaf(sA[nt][e & 3], SC_L2E, mbe)));  \
        pb.hh[e] = __float2bfloat16(EXP2F(fmaf(sB[nt][e & 3], SC_L2E, mbe)));  \
      }                                                                        \
      pbA[c] = pa.s8; pbB[c] = pb.s8;                                          \
    }                                                                          \
    __builtin_amdgcn_s_setprio(1);                                             \
    laccA = __builtin_amdgcn_mfma_f32_16x16x32_bf16(ones8, pbA[0], laccA, 0, 0, 0); \
    laccA = __builtin_amdgcn_mfma_f32_16x16x32_bf16(ones8, pbA[1], laccA, 0, 0, 0); \
    laccB = __builtin_amdgcn_mfma_f32_16x16x32_bf16(ones8, pbB[0], laccB, 0, 0, 0); \
    laccB = __builtin_amdgcn_mfma_f32_16x16x32_bf16(ones8, pbB[1], laccB, 0, 0, 0); \
    _Pragma("unroll") for (int dt = 0; dt < 4; ++dt) {                         \
      const int d = dt * 16 + l15;                                             \
      const int sw2 = (d & 7) << 4;                                            \
      const short8 v0 = *(const short8*)(Vs[CUR] + d * 128 + ((g * 16) ^ sw2)); \
      const short8 v1 = *(const short8*)(Vs[CUR] + d * 128 + ((64 + g * 16) ^ sw2)); \
      f32x4 oa = oaccA[dt], ob = oaccB[dt];                                    \
      oa = __builtin_amdgcn_mfma_f32_16x16x32_bf16(v0, pbA[0], oa, 0, 0, 0);   \
      oa = __builtin_amdgcn_mfma_f32_16x16x32_bf16(v1, pbA[1], oa, 0, 0, 0);   \
      ob = __builtin_amdgcn_mfma_f32_16x16x32_bf16(v0, pbB[0], ob, 0, 0, 0);   \
      ob = __builtin_amdgcn_mfma_f32_16x16x32_bf16(v1, pbB[1], ob, 0, 0, 0);   \
      oaccA[dt] = oa; oaccB[dt] = ob;                                          \
    }                                                                          \
    __builtin_amdgcn_s_setprio(0);                                             \
    if (SYNC == 4) { asm volatile("s_waitcnt vmcnt(4)" ::: "memory"); }        \
    else if (SYNC == 0) { asm volatile("s_waitcnt vmcnt(0)" ::: "memory"); }   \
    if (SYNC >= 0) {                                                           \
      __builtin_amdgcn_s_barrier();                                            \
      __builtin_amdgcn_sched_barrier(0);                                       \
    }                                                                          \
  }

__global__ __launch_bounds__(256, 2) void k_attn(
    const __hip_bfloat16* __restrict__ Qb, const __hip_bfloat16* __restrict__ Kb,
    const __hip_bfloat16* __restrict__ Vt, const float* __restrict__ bias2,
    float* __restrict__ out) {
  __shared__ char Ks[3][8192];              // [64 key-slots][64 d] bf16, permuted keys
  __shared__ char Vs[3][8192];              // [64 d][64 keys] bf16, natural order
  const int orig = blockIdx.x;
  const int swz = (orig & 7) * 64 + (orig >> 3);   // bijective; 4 heads per XCD
  const int bh = swz >> 4, qb = swz & 15;
  const int b = bh >> 4, h = bh & 15;
  const int tid = threadIdx.x, w = tid >> 6, lane = tid & 63;
  const int g = lane >> 4, l15 = lane & 15;
  const char* Qc = (const char*)(Qb + (size_t)bh * 131072);
  const char* Kc = (const char*)(Kb + (size_t)bh * 131072);
  const char* Vc = (const char*)(Vt + (size_t)bh * 131072);

  const int l8 = lane >> 3, l7 = lane & 7;
  const int vswz = ((l7 ^ l8) << 4);        // pre-swizzled global 16B slot in 128B row

  // Q B-fragments for the wave's TWO q-tiles: lane holds Q[q][k = kc*32 + g*8..+7]
  short8 aq[2][2];
  const int arow0 = qb * 128 + w * 32 + l15;          // q-tile A
#pragma unroll
  for (int qt = 0; qt < 2; ++qt)
#pragma unroll
    for (int kc = 0; kc < 2; ++kc)
      aq[qt][kc] = *(const short8*)(Qc + (size_t)(arow0 + qt * 16) * 128 + kc * 64 + g * 16);

  f32x4 oaccA[4], oaccB[4];                 // O^T per q-tile
#pragma unroll
  for (int i = 0; i < 4; ++i) {
    oaccA[i] = (f32x4){0.f, 0.f, 0.f, 0.f};
    oaccB[i] = (f32x4){0.f, 0.f, 0.f, 0.f};
  }
  f32x4 laccA = (f32x4){0.f, 0.f, 0.f, 0.f};
  f32x4 laccB = (f32x4){0.f, 0.f, 0.f, 0.f};
  const short8 ones8 = {(short)0x3F80, (short)0x3F80, (short)0x3F80, (short)0x3F80,
                        (short)0x3F80, (short)0x3F80, (short)0x3F80, (short)0x3F80};

  // prologue: stage tiles 0,1; wave w fills chunks w*2, w*2+1 (K permuted; r12 map)
  const char* kst[2];
  const char* vst[2];
#pragma unroll
  for (int j = 0; j < 2; ++j) {
    const int ch = w * 2 + j;
    const int s = ch * 8 + l8;              // LDS slot-row this lane fills
    const int nt0 = s >> 4, gg = (s >> 2) & 3, rr = s & 3;
    const int kap = (nt0 >> 1) * 32 + gg * 8 + ((nt0 & 1) << 2) + rr;  // actual key
    kst[j] = Kc + (size_t)kap * 128 + vswz;
    vst[j] = Vc + (size_t)s * 4096 + vswz;
  }
#pragma unroll
  for (int tpre = 0; tpre < 2; ++tpre) {
#pragma unroll
    for (int j = 0; j < 2; ++j) {
      gload16(kst[j], Ks[tpre] + (w * 2 + j) * 1024);
      gload16(vst[j], Vs[tpre] + (w * 2 + j) * 1024);
    }
    kst[0] += 8192; kst[1] += 8192; vst[0] += 128; vst[1] += 128;
  }
  asm volatile("s_waitcnt vmcnt(4)" ::: "memory");   // tile 0 landed; tile 1 in flight
  __builtin_amdgcn_s_barrier();
  __builtin_amdgcn_sched_barrier(0);

  const float* mbp = bias2 + b * 2048;
  for (int k = 0; k < 10; ++k) {            // t = 0..29, depth-2 prefetch
    ATTN_BODY(0, 2, 1, 4)
    ATTN_BODY(1, 0, 1, 4)
    ATTN_BODY(2, 1, 1, 4)
  }
  ATTN_BODY(0, 2, 0, 0)                     // t=30: drain (tile 31 lands)
  ATTN_BODY(1, 0, 0, -1)                    // t=31: compute only

  // epilogue: per q-tile, lacc rows all equal the full denominator
  const float rlA = 1.0f / laccA[0];
  const float rlB = 1.0f / laccB[0];
  float* orowA = out + ((size_t)(b * 2048 + arow0)) * 1024 + h * 64;
  float* orowB = orowA + 16 * 1024;
#pragma unroll
  for (int dt = 0; dt < 4; ++dt) {
    float4 stA, stB;
    stA.x = oaccA[dt][0] * rlA; stA.y = oaccA[dt][1] * rlA;
    stA.z = oaccA[dt][2] * rlA; stA.w = oaccA[dt][3] * rlA;
    stB.x = oaccB[dt][0] * rlB; stB.y = oaccB[dt][1] * rlB;
    stB.z = oaccB[dt][2] * rlB; stB.w = oaccB[dt][3] * rlB;
    *(float4*)(orowA + dt * 16 + g * 4) = stA;
    *(float4*)(orowB + dt * 16 + g * 4) = stB;
  }
}

// ---------------- launcher ----------------
extern "C" void kernel_launch(void* const* d_in, const int* in_sizes, int n_in,
                              void* d_out, int out_size, void* d_ws, size_t ws_size,
                              hipStream_t stream) {
  const float* q   = (const float*)d_in[0];
  const float* k   = (const float*)d_in[1];
  const float* v   = (const float*)d_in[2];
  const int* mask  = (const int*)d_in[3];
  const float* Wq  = (const float*)d_in[4];
  const float* bq  = (const float*)d_in[5];
  const float* Wk  = (const float*)d_in[6];
  const float* bk  = (const float*)d_in[7];
  const float* Wv  = (const float*)d_in[8];
  const float* bv  = (const float*)d_in[9];
  float* out = (float*)d_out;
  char* ws = (char*)d_ws;
  __hip_bfloat16* Xb = (__hip_bfloat16*)(ws);
  __hip_bfloat16* Wt = (__hip_bfloat16*)(ws + 25165824);
  __hip_bfloat16* Qb = (__hip_bfloat16*)(ws + 31457280);
  __hip_bfloat16* Kb = (__hip_bfloat16*)(ws + 39845888);
  __hip_bfloat16* Vt = (__hip_bfloat16*)(ws + 48234496);
  float* bias2      = (float*)(ws + 56623104);   // 4096 floats

  k_cvt<<<dim3(6912), dim3(256), 0, stream>>>(q, k, v, Xb, Wq, Wk, Wv, Wt, mask, bias2);
  k_proj<<<dim3(768), dim3(256), 0, stream>>>(Xb, Wt, bq, bk, bv, Qb, Kb, Vt);
  k_attn<<<dim3(512), dim3(256), 0, stream>>>(Qb, Kb, Vt, bias2, out);
}